// Round 1
// baseline (13182.108 us; speedup 1.0000x reference)
//
#include <hip/hip_runtime.h>
#include <cstdint>
#include <cstddef>

#define NN 50000
#define EE 800000
#define FIN 512
#define HIDC 16
#define NH 8
#define HCH 128
#define NLBL 40
#define ETOT (EE + NN)
#define NEG_SLOPE 0.2f
#define ELU_A 0.2f
#define BN_EPS 1e-5f

// ---------------- GEMM: C[M,N] = A[M,K] @ B[K,N], fp32, 64x64x16 tiles ----------------
__global__ __launch_bounds__(256) void k_gemm(const float* __restrict__ A,
                                              const float* __restrict__ B,
                                              float* __restrict__ C,
                                              int M, int N, int K)
{
    __shared__ float As[16][68];
    __shared__ float Bs[16][68];
    const int bm = blockIdx.y * 64;
    const int bn = blockIdx.x * 64;
    const int tid = threadIdx.x;
    const int tm = (tid >> 4) << 2;
    const int tn = (tid & 15) << 2;
    const int ar = tid >> 2;          // 0..63  (A tile row)
    const int ac = (tid & 3) << 2;    // 0,4,8,12 (A tile col, k)
    const int br = tid >> 4;          // 0..15  (B tile row, k)
    const int bc = (tid & 15) << 2;   // 0..60  (B tile col)
    float acc[4][4] = {};
    for (int k0 = 0; k0 < K; k0 += 16) {
        float4 av = make_float4(0.f, 0.f, 0.f, 0.f);
        if (bm + ar < M)
            av = *(const float4*)&A[(size_t)(bm + ar) * K + k0 + ac];
        As[ac + 0][ar] = av.x; As[ac + 1][ar] = av.y;
        As[ac + 2][ar] = av.z; As[ac + 3][ar] = av.w;
        float4 bv = make_float4(0.f, 0.f, 0.f, 0.f);
        if (bn + bc + 3 < N) {
            bv = *(const float4*)&B[(size_t)(k0 + br) * N + bn + bc];
        } else {
            float t[4] = {0.f, 0.f, 0.f, 0.f};
            for (int j = 0; j < 4; ++j)
                if (bn + bc + j < N) t[j] = B[(size_t)(k0 + br) * N + bn + bc + j];
            bv = make_float4(t[0], t[1], t[2], t[3]);
        }
        Bs[br][bc + 0] = bv.x; Bs[br][bc + 1] = bv.y;
        Bs[br][bc + 2] = bv.z; Bs[br][bc + 3] = bv.w;
        __syncthreads();
        #pragma unroll
        for (int kk = 0; kk < 16; ++kk) {
            float a0 = As[kk][tm], a1 = As[kk][tm + 1], a2 = As[kk][tm + 2], a3 = As[kk][tm + 3];
            float b0 = Bs[kk][tn], b1 = Bs[kk][tn + 1], b2 = Bs[kk][tn + 2], b3 = Bs[kk][tn + 3];
            acc[0][0] += a0 * b0; acc[0][1] += a0 * b1; acc[0][2] += a0 * b2; acc[0][3] += a0 * b3;
            acc[1][0] += a1 * b0; acc[1][1] += a1 * b1; acc[1][2] += a1 * b2; acc[1][3] += a1 * b3;
            acc[2][0] += a2 * b0; acc[2][1] += a2 * b1; acc[2][2] += a2 * b2; acc[2][3] += a2 * b3;
            acc[3][0] += a3 * b0; acc[3][1] += a3 * b1; acc[3][2] += a3 * b2; acc[3][3] += a3 * b3;
        }
        __syncthreads();
    }
    for (int i = 0; i < 4; ++i) {
        int r = bm + tm + i;
        if (r >= M) break;
        for (int j = 0; j < 4; ++j) {
            int c = bn + tn + j;
            if (c < N) C[(size_t)r * N + c] = acc[i][j];
        }
    }
}

// ---------------- per-(node,head) attention logits, H=8, C=16 ----------------
__global__ __launch_bounds__(256) void k_alpha(const float* __restrict__ h,
                                               const float* __restrict__ a_s,
                                               const float* __restrict__ a_d,
                                               float* __restrict__ as_o,
                                               float* __restrict__ ad_o)
{
    int idx = blockIdx.x * blockDim.x + threadIdx.x;   // n*NH + hh
    if (idx >= NN * NH) return;
    int hh = idx & (NH - 1);
    const float4* hp = (const float4*)&h[(size_t)idx * HIDC];  // n*128 + hh*16
    const float4* ap = (const float4*)&a_s[hh * HIDC];
    const float4* dp = (const float4*)&a_d[hh * HIDC];
    float ss = 0.f, dd = 0.f;
    #pragma unroll
    for (int j = 0; j < 4; ++j) {
        float4 v = hp[j], a = ap[j], d = dp[j];
        ss += v.x * a.x + v.y * a.y + v.z * a.z + v.w * a.w;
        dd += v.x * d.x + v.y * d.y + v.z * d.z + v.w * d.w;
    }
    as_o[idx] = ss;
    ad_o[idx] = dd;
}

// ---------------- edge softmax denominator (no max pass; logits are O(1)) ----------------
__global__ __launch_bounds__(256) void k_edge_sum(const int* __restrict__ ei,
                                                  const float* __restrict__ as,
                                                  const float* __restrict__ ad,
                                                  float* __restrict__ s)
{
    int idx = blockIdx.x * blockDim.x + threadIdx.x;   // e*NH + hh
    if (idx >= ETOT * NH) return;
    int e = idx >> 3, hh = idx & 7;
    int src, dst;
    if (e < EE) { src = ei[e]; dst = ei[EE + e]; }
    else        { src = dst = e - EE; }
    float l = as[src * NH + hh] + ad[dst * NH + hh];
    l = l > 0.f ? l : NEG_SLOPE * l;
    atomicAdd(&s[dst * NH + hh], __expf(l));
}

// ---------------- message pass: out[dst] += alpha * h[src], 16 ch per thread ----------------
__global__ __launch_bounds__(256) void k_edge_msg(const int* __restrict__ ei,
                                                  const float* __restrict__ as,
                                                  const float* __restrict__ ad,
                                                  const float* __restrict__ s,
                                                  const float* __restrict__ h,
                                                  float* __restrict__ out)
{
    int idx = blockIdx.x * blockDim.x + threadIdx.x;   // e*NH + hh
    if (idx >= ETOT * NH) return;
    int e = idx >> 3, hh = idx & 7;
    int src, dst;
    if (e < EE) { src = ei[e]; dst = ei[EE + e]; }
    else        { src = dst = e - EE; }
    float l = as[src * NH + hh] + ad[dst * NH + hh];
    l = l > 0.f ? l : NEG_SLOPE * l;
    float w = __expf(l) / (s[dst * NH + hh] + 1e-16f);
    const float4* hp = (const float4*)&h[((size_t)src * NH + hh) * HIDC];
    float* op = &out[((size_t)dst * NH + hh) * HIDC];
    #pragma unroll
    for (int j = 0; j < 4; ++j) {
        float4 v = hp[j];
        atomicAdd(op + 4 * j + 0, w * v.x);
        atomicAdd(op + 4 * j + 1, w * v.y);
        atomicAdd(op + 4 * j + 2, w * v.z);
        atomicAdd(op + 4 * j + 3, w * v.w);
    }
}

// ---------------- layer-2 (1 head, 40 ch) variants ----------------
__global__ __launch_bounds__(256) void k_alpha2(const float* __restrict__ h2,
                                                const float* __restrict__ a_s,
                                                const float* __restrict__ a_d,
                                                float* __restrict__ as_o,
                                                float* __restrict__ ad_o)
{
    int n = blockIdx.x * blockDim.x + threadIdx.x;
    if (n >= NN) return;
    const float4* hp = (const float4*)&h2[(size_t)n * NLBL];
    float ss = 0.f, dd = 0.f;
    #pragma unroll
    for (int j = 0; j < 10; ++j) {
        float4 v = hp[j];
        float4 a = ((const float4*)a_s)[j];
        float4 d = ((const float4*)a_d)[j];
        ss += v.x * a.x + v.y * a.y + v.z * a.z + v.w * a.w;
        dd += v.x * d.x + v.y * d.y + v.z * d.z + v.w * d.w;
    }
    as_o[n] = ss;
    ad_o[n] = dd;
}

__global__ __launch_bounds__(256) void k_edge_sum2(const int* __restrict__ ei,
                                                   const float* __restrict__ as,
                                                   const float* __restrict__ ad,
                                                   float* __restrict__ s)
{
    int e = blockIdx.x * blockDim.x + threadIdx.x;
    if (e >= ETOT) return;
    int src, dst;
    if (e < EE) { src = ei[e]; dst = ei[EE + e]; }
    else        { src = dst = e - EE; }
    float l = as[src] + ad[dst];
    l = l > 0.f ? l : NEG_SLOPE * l;
    atomicAdd(&s[dst], __expf(l));
}

__global__ __launch_bounds__(256) void k_edge_msg2(const int* __restrict__ ei,
                                                   const float* __restrict__ as,
                                                   const float* __restrict__ ad,
                                                   const float* __restrict__ s,
                                                   const float* __restrict__ h2,
                                                   float* __restrict__ out)
{
    int idx = blockIdx.x * blockDim.x + threadIdx.x;   // e*10 + j
    if (idx >= ETOT * 10) return;
    int e = idx / 10, j = idx - e * 10;
    int src, dst;
    if (e < EE) { src = ei[e]; dst = ei[EE + e]; }
    else        { src = dst = e - EE; }
    float l = as[src] + ad[dst];
    l = l > 0.f ? l : NEG_SLOPE * l;
    float w = __expf(l) / (s[dst] + 1e-16f);
    float4 v = *(const float4*)&h2[(size_t)src * NLBL + j * 4];
    float* op = &out[(size_t)dst * NLBL + j * 4];
    atomicAdd(op + 0, w * v.x);
    atomicAdd(op + 1, w * v.y);
    atomicAdd(op + 2, w * v.z);
    atomicAdd(op + 3, w * v.w);
}

// ---------------- init output with bias; fused BN+ELU ----------------
__global__ __launch_bounds__(256) void k_init_bias(float* __restrict__ out,
                                                   const float* __restrict__ b,
                                                   int total, int C)
{
    int idx = blockIdx.x * blockDim.x + threadIdx.x;
    if (idx >= total) return;
    out[idx] = b[idx % C];
}

__global__ __launch_bounds__(256) void k_bn_elu(float* __restrict__ x,
                                                const float* __restrict__ g,
                                                const float* __restrict__ be,
                                                const float* __restrict__ rm,
                                                const float* __restrict__ rv)
{
    int idx = blockIdx.x * blockDim.x + threadIdx.x;
    if (idx >= NN * HCH) return;
    int c = idx & (HCH - 1);
    float y = (x[idx] - rm[c]) * (g[c] * rsqrtf(rv[c] + BN_EPS)) + be[c];
    x[idx] = y > 0.f ? y : ELU_A * expm1f(y);
}

extern "C" void kernel_launch(void* const* d_in, const int* in_sizes, int n_in,
                              void* d_out, int out_size, void* d_ws, size_t ws_size,
                              hipStream_t stream)
{
    const float* x   = (const float*)d_in[0];
    const int*   ei  = (const int*)d_in[1];
    const float* W0  = (const float*)d_in[2];
    const float* as0 = (const float*)d_in[3];
    const float* ad0 = (const float*)d_in[4];
    const float* b0  = (const float*)d_in[5];
    const float* g0  = (const float*)d_in[6];
    const float* be0 = (const float*)d_in[7];
    const float* rm0 = (const float*)d_in[8];
    const float* rv0 = (const float*)d_in[9];
    const float* W1  = (const float*)d_in[10];
    const float* as1 = (const float*)d_in[11];
    const float* ad1 = (const float*)d_in[12];
    const float* b1  = (const float*)d_in[13];
    const float* g1  = (const float*)d_in[14];
    const float* be1 = (const float*)d_in[15];
    const float* rm1 = (const float*)d_in[16];
    const float* rv1 = (const float*)d_in[17];
    const float* W2  = (const float*)d_in[18];
    const float* a_s2 = (const float*)d_in[19];
    const float* a_d2 = (const float*)d_in[20];
    const float* b2  = (const float*)d_in[21];
    float* out = (float*)d_out;

    char* ws = (char*)d_ws;
    size_t off = 0;
    auto alloc = [&](size_t bytes) {
        float* p = (float*)(ws + off);
        off += (bytes + 255) & ~(size_t)255;
        return p;
    };
    float* hbuf = alloc((size_t)NN * HCH * 4);   // GEMM output / gather source
    float* fbuf = alloc((size_t)NN * HCH * 4);   // aggregated features
    float* asb  = alloc((size_t)NN * NH * 4);
    float* adb  = alloc((size_t)NN * NH * 4);
    float* sb   = alloc((size_t)NN * NH * 4);
    float* h2   = hbuf;                           // reuse: hbuf dead after layer-1 msg

    const int T = 256;
    const int gEH  = (ETOT * NH + T - 1) / T;     // 6.8M threads
    const int gNC  = (NN * HCH + T - 1) / T;
    const int gNH  = (NN * NH + T - 1) / T;

    // ---------- layer 0 ----------
    k_gemm<<<dim3(HCH / 64, (NN + 63) / 64), T, 0, stream>>>(x, W0, hbuf, NN, HCH, FIN);
    k_alpha<<<gNH, T, 0, stream>>>(hbuf, as0, ad0, asb, adb);
    hipMemsetAsync(sb, 0, (size_t)NN * NH * 4, stream);
    k_edge_sum<<<gEH, T, 0, stream>>>(ei, asb, adb, sb);
    k_init_bias<<<gNC, T, 0, stream>>>(fbuf, b0, NN * HCH, HCH);
    k_edge_msg<<<gEH, T, 0, stream>>>(ei, asb, adb, sb, hbuf, fbuf);
    k_bn_elu<<<gNC, T, 0, stream>>>(fbuf, g0, be0, rm0, rv0);

    // ---------- layer 1 ----------
    k_gemm<<<dim3(HCH / 64, (NN + 63) / 64), T, 0, stream>>>(fbuf, W1, hbuf, NN, HCH, HCH);
    k_alpha<<<gNH, T, 0, stream>>>(hbuf, as1, ad1, asb, adb);
    hipMemsetAsync(sb, 0, (size_t)NN * NH * 4, stream);
    k_edge_sum<<<gEH, T, 0, stream>>>(ei, asb, adb, sb);
    // fbuf was gemm input; gemm is complete (stream order) -> reuse as layer-1 output
    k_init_bias<<<gNC, T, 0, stream>>>(fbuf, b1, NN * HCH, HCH);
    k_edge_msg<<<gEH, T, 0, stream>>>(ei, asb, adb, sb, hbuf, fbuf);
    k_bn_elu<<<gNC, T, 0, stream>>>(fbuf, g1, be1, rm1, rv1);

    // ---------- layer 2 (1 head, 40 channels, accumulate into d_out) ----------
    k_gemm<<<dim3(1, (NN + 63) / 64), T, 0, stream>>>(fbuf, W2, h2, NN, NLBL, HCH);
    k_alpha2<<<(NN + T - 1) / T, T, 0, stream>>>(h2, a_s2, a_d2, asb, adb);
    hipMemsetAsync(sb, 0, (size_t)NN * 4, stream);
    k_edge_sum2<<<(ETOT + T - 1) / T, T, 0, stream>>>(ei, asb, adb, sb);
    k_init_bias<<<(NN * NLBL + T - 1) / T, T, 0, stream>>>(out, b2, NN * NLBL, NLBL);
    k_edge_msg2<<<(ETOT * 10 + T - 1) / T, T, 0, stream>>>(ei, asb, adb, sb, h2, out);
}

// Round 2
// 737.961 us; speedup vs baseline: 17.8629x; 17.8629x over previous
//
#include <hip/hip_runtime.h>
#include <cstdint>
#include <cstddef>

#define NN 50000
#define EE 800000
#define FIN 512
#define HIDC 16
#define NH 8
#define HCH 128
#define NLBL 40
#define ETOT (EE + NN)
#define NEG_SLOPE 0.2f
#define ELU_A 0.2f
#define BN_EPS 1e-5f

// ---------------- GEMM: C[M,N] = A[M,K] @ B[K,N], fp32, 64x64x16 tiles ----------------
__global__ __launch_bounds__(256) void k_gemm(const float* __restrict__ A,
                                              const float* __restrict__ B,
                                              float* __restrict__ C,
                                              int M, int N, int K)
{
    __shared__ float As[16][68];
    __shared__ float Bs[16][68];
    const int bm = blockIdx.y * 64;
    const int bn = blockIdx.x * 64;
    const int tid = threadIdx.x;
    const int tm = (tid >> 4) << 2;
    const int tn = (tid & 15) << 2;
    const int ar = tid >> 2;
    const int ac = (tid & 3) << 2;
    const int br = tid >> 4;
    const int bc = (tid & 15) << 2;
    float acc[4][4] = {};
    for (int k0 = 0; k0 < K; k0 += 16) {
        float4 av = make_float4(0.f, 0.f, 0.f, 0.f);
        if (bm + ar < M)
            av = *(const float4*)&A[(size_t)(bm + ar) * K + k0 + ac];
        As[ac + 0][ar] = av.x; As[ac + 1][ar] = av.y;
        As[ac + 2][ar] = av.z; As[ac + 3][ar] = av.w;
        float4 bv = make_float4(0.f, 0.f, 0.f, 0.f);
        if (bn + bc + 3 < N) {
            bv = *(const float4*)&B[(size_t)(k0 + br) * N + bn + bc];
        } else {
            float t[4] = {0.f, 0.f, 0.f, 0.f};
            for (int j = 0; j < 4; ++j)
                if (bn + bc + j < N) t[j] = B[(size_t)(k0 + br) * N + bn + bc + j];
            bv = make_float4(t[0], t[1], t[2], t[3]);
        }
        Bs[br][bc + 0] = bv.x; Bs[br][bc + 1] = bv.y;
        Bs[br][bc + 2] = bv.z; Bs[br][bc + 3] = bv.w;
        __syncthreads();
        #pragma unroll
        for (int kk = 0; kk < 16; ++kk) {
            float a0 = As[kk][tm], a1 = As[kk][tm + 1], a2 = As[kk][tm + 2], a3 = As[kk][tm + 3];
            float b0 = Bs[kk][tn], b1 = Bs[kk][tn + 1], b2 = Bs[kk][tn + 2], b3 = Bs[kk][tn + 3];
            acc[0][0] += a0 * b0; acc[0][1] += a0 * b1; acc[0][2] += a0 * b2; acc[0][3] += a0 * b3;
            acc[1][0] += a1 * b0; acc[1][1] += a1 * b1; acc[1][2] += a1 * b2; acc[1][3] += a1 * b3;
            acc[2][0] += a2 * b0; acc[2][1] += a2 * b1; acc[2][2] += a2 * b2; acc[2][3] += a2 * b3;
            acc[3][0] += a3 * b0; acc[3][1] += a3 * b1; acc[3][2] += a3 * b2; acc[3][3] += a3 * b3;
        }
        __syncthreads();
    }
    for (int i = 0; i < 4; ++i) {
        int r = bm + tm + i;
        if (r >= M) break;
        for (int j = 0; j < 4; ++j) {
            int c = bn + tn + j;
            if (c < N) C[(size_t)r * N + c] = acc[i][j];
        }
    }
}

// ---------------- per-(node,head) attention logits ----------------
__global__ __launch_bounds__(256) void k_alpha(const float* __restrict__ h,
                                               const float* __restrict__ a_s,
                                               const float* __restrict__ a_d,
                                               float* __restrict__ as_o,
                                               float* __restrict__ ad_o)
{
    int idx = blockIdx.x * blockDim.x + threadIdx.x;   // n*NH + hh
    if (idx >= NN * NH) return;
    int hh = idx & (NH - 1);
    const float4* hp = (const float4*)&h[(size_t)idx * HIDC];
    const float4* ap = (const float4*)&a_s[hh * HIDC];
    const float4* dp = (const float4*)&a_d[hh * HIDC];
    float ss = 0.f, dd = 0.f;
    #pragma unroll
    for (int j = 0; j < 4; ++j) {
        float4 v = hp[j], a = ap[j], d = dp[j];
        ss += v.x * a.x + v.y * a.y + v.z * a.z + v.w * a.w;
        dd += v.x * d.x + v.y * d.y + v.z * d.z + v.w * d.w;
    }
    as_o[idx] = ss;
    ad_o[idx] = dd;
}

__global__ __launch_bounds__(256) void k_alpha2(const float* __restrict__ h2,
                                                const float* __restrict__ a_s,
                                                const float* __restrict__ a_d,
                                                float* __restrict__ as_o,
                                                float* __restrict__ ad_o)
{
    int n = blockIdx.x * blockDim.x + threadIdx.x;
    if (n >= NN) return;
    const float4* hp = (const float4*)&h2[(size_t)n * NLBL];
    float ss = 0.f, dd = 0.f;
    #pragma unroll
    for (int j = 0; j < 10; ++j) {
        float4 v = hp[j];
        float4 a = ((const float4*)a_s)[j];
        float4 d = ((const float4*)a_d)[j];
        ss += v.x * a.x + v.y * a.y + v.z * a.z + v.w * a.w;
        dd += v.x * d.x + v.y * d.y + v.z * d.z + v.w * d.w;
    }
    as_o[n] = ss;
    ad_o[n] = dd;
}

// ---------------- CSR build ----------------
__global__ __launch_bounds__(256) void k_hist(const int* __restrict__ ei,
                                              int* __restrict__ deg)
{
    int e = blockIdx.x * blockDim.x + threadIdx.x;
    if (e >= ETOT) return;
    int dst = (e < EE) ? ei[EE + e] : (e - EE);
    atomicAdd(&deg[dst], 1);
}

__global__ __launch_bounds__(1024) void k_scan(const int* __restrict__ deg,
                                               int* __restrict__ row_ptr,
                                               int* __restrict__ cursor)
{
    __shared__ int sm[1024];
    __shared__ int carry;
    int tid = threadIdx.x;
    if (tid == 0) carry = 0;
    __syncthreads();
    for (int base = 0; base < NN; base += 8192) {
        int v[8];
        int s = 0;
        int i0 = base + tid * 8;
        #pragma unroll
        for (int j = 0; j < 8; ++j) {
            int i = i0 + j;
            v[j] = (i < NN) ? deg[i] : 0;
            s += v[j];
        }
        sm[tid] = s;
        __syncthreads();
        for (int ofs = 1; ofs < 1024; ofs <<= 1) {
            int t = (tid >= ofs) ? sm[tid - ofs] : 0;
            __syncthreads();
            sm[tid] += t;
            __syncthreads();
        }
        int excl = sm[tid] - s + carry;
        #pragma unroll
        for (int j = 0; j < 8; ++j) {
            int i = i0 + j;
            if (i < NN) { row_ptr[i] = excl; cursor[i] = excl; }
            excl += v[j];
        }
        int total = sm[1023];
        __syncthreads();
        if (tid == 0) carry += total;
        __syncthreads();
    }
    if (tid == 0) row_ptr[NN] = carry;   // == ETOT
}

__global__ __launch_bounds__(256) void k_scatter(const int* __restrict__ ei,
                                                 int* __restrict__ cursor,
                                                 int* __restrict__ csr_src)
{
    int e = blockIdx.x * blockDim.x + threadIdx.x;
    if (e >= ETOT) return;
    int src, dst;
    if (e < EE) { src = ei[e]; dst = ei[EE + e]; }
    else        { src = dst = e - EE; }
    int pos = atomicAdd(&cursor[dst], 1);
    csr_src[pos] = src;
}

// ---------------- pull aggregation, fused softmax-norm + bias + BN + ELU ----------------
// one wave per node; lane owns channels (lane) and (64+lane)
__global__ __launch_bounds__(256) void k_agg(const int* __restrict__ row_ptr,
                                             const int* __restrict__ csr_src,
                                             const float* __restrict__ h,
                                             const float* __restrict__ as,
                                             const float* __restrict__ ad,
                                             const float* __restrict__ b,
                                             const float* __restrict__ g,
                                             const float* __restrict__ be,
                                             const float* __restrict__ rm,
                                             const float* __restrict__ rv,
                                             float* __restrict__ out)
{
    int n = blockIdx.x * 4 + (threadIdx.x >> 6);
    if (n >= NN) return;
    int lane = threadIdx.x & 63;
    int hh0 = lane >> 4;                 // head of channel lane   (0..3)
    // head of channel 64+lane is hh0+4
    float adv0 = ad[n * NH + hh0];
    float adv1 = ad[n * NH + hh0 + 4];
    float acc0 = 0.f, acc1 = 0.f, sw0 = 0.f, sw1 = 0.f;
    int jb = row_ptr[n], je = row_ptr[n + 1];
    for (int j = jb; j < je; ++j) {
        int src = csr_src[j];
        float l0 = as[src * NH + hh0] + adv0;
        float l1 = as[src * NH + hh0 + 4] + adv1;
        l0 = l0 > 0.f ? l0 : NEG_SLOPE * l0;
        l1 = l1 > 0.f ? l1 : NEG_SLOPE * l1;
        float w0 = __expf(l0);
        float w1 = __expf(l1);
        sw0 += w0; sw1 += w1;
        acc0 += w0 * h[(size_t)src * HCH + lane];
        acc1 += w1 * h[(size_t)src * HCH + 64 + lane];
    }
    int c0 = lane, c1 = 64 + lane;
    float r0 = acc0 / (sw0 + 1e-16f) + b[c0];
    float r1 = acc1 / (sw1 + 1e-16f) + b[c1];
    r0 = (r0 - rm[c0]) * (g[c0] * rsqrtf(rv[c0] + BN_EPS)) + be[c0];
    r1 = (r1 - rm[c1]) * (g[c1] * rsqrtf(rv[c1] + BN_EPS)) + be[c1];
    out[(size_t)n * HCH + c0] = r0 > 0.f ? r0 : ELU_A * expm1f(r0);
    out[(size_t)n * HCH + c1] = r1 > 0.f ? r1 : ELU_A * expm1f(r1);
}

// layer-2: 1 head, 40 channels, +bias only, straight to d_out
__global__ __launch_bounds__(256) void k_agg2(const int* __restrict__ row_ptr,
                                              const int* __restrict__ csr_src,
                                              const float* __restrict__ h2,
                                              const float* __restrict__ as,
                                              const float* __restrict__ ad,
                                              const float* __restrict__ b,
                                              float* __restrict__ out)
{
    int n = blockIdx.x * 4 + (threadIdx.x >> 6);
    if (n >= NN) return;
    int lane = threadIdx.x & 63;
    float adv = ad[n];
    float acc = 0.f, sw = 0.f;
    int jb = row_ptr[n], je = row_ptr[n + 1];
    for (int j = jb; j < je; ++j) {
        int src = csr_src[j];
        float l = as[src] + adv;
        l = l > 0.f ? l : NEG_SLOPE * l;
        float w = __expf(l);
        sw += w;
        if (lane < NLBL) acc += w * h2[(size_t)src * NLBL + lane];
    }
    if (lane < NLBL) out[(size_t)n * NLBL + lane] = acc / (sw + 1e-16f) + b[lane];
}

extern "C" void kernel_launch(void* const* d_in, const int* in_sizes, int n_in,
                              void* d_out, int out_size, void* d_ws, size_t ws_size,
                              hipStream_t stream)
{
    const float* x   = (const float*)d_in[0];
    const int*   ei  = (const int*)d_in[1];
    const float* W0  = (const float*)d_in[2];
    const float* as0 = (const float*)d_in[3];
    const float* ad0 = (const float*)d_in[4];
    const float* b0  = (const float*)d_in[5];
    const float* g0  = (const float*)d_in[6];
    const float* be0 = (const float*)d_in[7];
    const float* rm0 = (const float*)d_in[8];
    const float* rv0 = (const float*)d_in[9];
    const float* W1  = (const float*)d_in[10];
    const float* as1 = (const float*)d_in[11];
    const float* ad1 = (const float*)d_in[12];
    const float* b1  = (const float*)d_in[13];
    const float* g1  = (const float*)d_in[14];
    const float* be1 = (const float*)d_in[15];
    const float* rm1 = (const float*)d_in[16];
    const float* rv1 = (const float*)d_in[17];
    const float* W2  = (const float*)d_in[18];
    const float* a_s2 = (const float*)d_in[19];
    const float* a_d2 = (const float*)d_in[20];
    const float* b2  = (const float*)d_in[21];
    float* out = (float*)d_out;

    char* ws = (char*)d_ws;
    size_t off = 0;
    auto alloc = [&](size_t bytes) {
        void* p = (void*)(ws + off);
        off += (bytes + 255) & ~(size_t)255;
        return p;
    };
    float* hbuf   = (float*)alloc((size_t)NN * HCH * 4);
    float* fbuf   = (float*)alloc((size_t)NN * HCH * 4);
    float* asb    = (float*)alloc((size_t)NN * NH * 4);
    float* adb    = (float*)alloc((size_t)NN * NH * 4);
    int*   deg    = (int*)alloc((size_t)NN * 4);
    int*   rowp   = (int*)alloc((size_t)(NN + 1) * 4);
    int*   cursor = (int*)alloc((size_t)NN * 4);
    int*   csrs   = (int*)alloc((size_t)ETOT * 4);
    float* h2     = hbuf;   // reuse: hbuf dead by layer 2

    const int T = 256;
    const int gE  = (ETOT + T - 1) / T;
    const int gNH = (NN * NH + T - 1) / T;
    const int gN4 = (NN + 3) / 4;

    // ---------- CSR build (reused by all 3 layers) ----------
    hipMemsetAsync(deg, 0, (size_t)NN * 4, stream);
    k_hist<<<gE, T, 0, stream>>>(ei, deg);
    k_scan<<<1, 1024, 0, stream>>>(deg, rowp, cursor);
    k_scatter<<<gE, T, 0, stream>>>(ei, cursor, csrs);

    // ---------- layer 0 ----------
    k_gemm<<<dim3(HCH / 64, (NN + 63) / 64), T, 0, stream>>>(x, W0, hbuf, NN, HCH, FIN);
    k_alpha<<<gNH, T, 0, stream>>>(hbuf, as0, ad0, asb, adb);
    k_agg<<<gN4, T, 0, stream>>>(rowp, csrs, hbuf, asb, adb, b0, g0, be0, rm0, rv0, fbuf);

    // ---------- layer 1 ----------
    k_gemm<<<dim3(HCH / 64, (NN + 63) / 64), T, 0, stream>>>(fbuf, W1, hbuf, NN, HCH, HCH);
    k_alpha<<<gNH, T, 0, stream>>>(hbuf, as1, ad1, asb, adb);
    k_agg<<<gN4, T, 0, stream>>>(rowp, csrs, hbuf, asb, adb, b1, g1, be1, rm1, rv1, fbuf);

    // ---------- layer 2 ----------
    k_gemm<<<dim3(1, (NN + 63) / 64), T, 0, stream>>>(fbuf, W2, h2, NN, NLBL, HCH);
    k_alpha2<<<(NN + T - 1) / T, T, 0, stream>>>(h2, a_s2, a_d2, asb, adb);
    k_agg2<<<gN4, T, 0, stream>>>(rowp, csrs, h2, asb, adb, b2, out);
}

// Round 3
// 719.396 us; speedup vs baseline: 18.3238x; 1.0258x over previous
//
#include <hip/hip_runtime.h>
#include <hip/hip_bf16.h>
#include <cstdint>
#include <cstddef>

#define NN 50000
#define EE 800000
#define FIN 512
#define HIDC 16
#define NH 8
#define HCH 128
#define NLBL 40
#define NLBLP 48
#define ETOT (EE + NN)
#define NEG_SLOPE 0.2f
#define ELU_A 0.2f
#define BN_EPS 1e-5f

typedef __attribute__((ext_vector_type(8))) short bf16x8;
typedef __attribute__((ext_vector_type(4))) float f32x4;

__device__ inline short f2b(float f) {
    __hip_bfloat16 h = __float2bfloat16(f);   // RNE
    return *reinterpret_cast<short*>(&h);
}

// ---------------- weight transpose + bf16 convert: Wt[n][k] = bf16(W[k][n]) ----------------
__global__ __launch_bounds__(256) void k_convW(const float* __restrict__ W,
                                               short* __restrict__ Wt,
                                               int K, int N, int Np)
{
    int idx = blockIdx.x * blockDim.x + threadIdx.x;
    if (idx >= Np * K) return;
    int n = idx / K, k = idx - n * K;
    float v = (n < N) ? W[(size_t)k * N + n] : 0.f;
    Wt[idx] = f2b(v);
}

// ---------------- MFMA GEMM: C[M,N] = A[M,K] @ Wt^T, per-wave 16xN strip ----------------
// A fragment (16x16x32): lane holds A[m=lane&15][k=quad*8+j], j=0..7 (16B)
// B fragment: lane holds B[k=quad*8+j][n=lane&15] = Wt[n][k..k+7] (16B contiguous)
// C/D: col=lane&15, row=quad*4+reg
template<int KDIM, int NTILES, bool A_BF16>
__global__ __launch_bounds__(256) void k_gemm_mfma(const void* __restrict__ Ap,
                                                   const short* __restrict__ Wt,
                                                   float* __restrict__ C,
                                                   int M, int N)
{
    const int wave = threadIdx.x >> 6;
    const int lane = threadIdx.x & 63;
    const int quad = lane >> 4;
    const int col  = lane & 15;
    int row = blockIdx.x * 64 + wave * 16 + col;
    int arow = row < M ? row : M - 1;

    f32x4 acc[NTILES];
    #pragma unroll
    for (int t = 0; t < NTILES; ++t) acc[t] = (f32x4){0.f, 0.f, 0.f, 0.f};

    #pragma unroll
    for (int k0 = 0; k0 < KDIM; k0 += 32) {
        bf16x8 afrag;
        if (A_BF16) {
            const short* Ab = (const short*)Ap;
            afrag = *(const bf16x8*)(Ab + (size_t)arow * KDIM + k0 + quad * 8);
        } else {
            const float* Af = (const float*)Ap;
            const float4* p = (const float4*)(Af + (size_t)arow * KDIM + k0 + quad * 8);
            float4 v0 = p[0], v1 = p[1];
            afrag[0] = f2b(v0.x); afrag[1] = f2b(v0.y);
            afrag[2] = f2b(v0.z); afrag[3] = f2b(v0.w);
            afrag[4] = f2b(v1.x); afrag[5] = f2b(v1.y);
            afrag[6] = f2b(v1.z); afrag[7] = f2b(v1.w);
        }
        #pragma unroll
        for (int t = 0; t < NTILES; ++t) {
            bf16x8 bfrag = *(const bf16x8*)(Wt + (size_t)(t * 16 + col) * KDIM + k0 + quad * 8);
            acc[t] = __builtin_amdgcn_mfma_f32_16x16x32_bf16(afrag, bfrag, acc[t], 0, 0, 0);
        }
    }

    int mbase = blockIdx.x * 64 + wave * 16 + quad * 4;
    #pragma unroll
    for (int t = 0; t < NTILES; ++t) {
        int c = t * 16 + col;
        if (c < N) {
            #pragma unroll
            for (int r = 0; r < 4; ++r) {
                int m = mbase + r;
                if (m < M) C[(size_t)m * N + c] = acc[t][r];
            }
        }
    }
}

// ---------------- per-(node,head) attention logits ----------------
__global__ __launch_bounds__(256) void k_alpha(const float* __restrict__ h,
                                               const float* __restrict__ a_s,
                                               const float* __restrict__ a_d,
                                               float* __restrict__ as_o,
                                               float* __restrict__ ad_o)
{
    int idx = blockIdx.x * blockDim.x + threadIdx.x;   // n*NH + hh
    if (idx >= NN * NH) return;
    int hh = idx & (NH - 1);
    const float4* hp = (const float4*)&h[(size_t)idx * HIDC];
    const float4* ap = (const float4*)&a_s[hh * HIDC];
    const float4* dp = (const float4*)&a_d[hh * HIDC];
    float ss = 0.f, dd = 0.f;
    #pragma unroll
    for (int j = 0; j < 4; ++j) {
        float4 v = hp[j], a = ap[j], d = dp[j];
        ss += v.x * a.x + v.y * a.y + v.z * a.z + v.w * a.w;
        dd += v.x * d.x + v.y * d.y + v.z * d.z + v.w * d.w;
    }
    as_o[idx] = ss;
    ad_o[idx] = dd;
}

__global__ __launch_bounds__(256) void k_alpha2(const float* __restrict__ h2,
                                                const float* __restrict__ a_s,
                                                const float* __restrict__ a_d,
                                                float* __restrict__ as_o,
                                                float* __restrict__ ad_o)
{
    int n = blockIdx.x * blockDim.x + threadIdx.x;
    if (n >= NN) return;
    const float4* hp = (const float4*)&h2[(size_t)n * NLBL];
    float ss = 0.f, dd = 0.f;
    #pragma unroll
    for (int j = 0; j < 10; ++j) {
        float4 v = hp[j];
        float4 a = ((const float4*)a_s)[j];
        float4 d = ((const float4*)a_d)[j];
        ss += v.x * a.x + v.y * a.y + v.z * a.z + v.w * a.w;
        dd += v.x * d.x + v.y * d.y + v.z * d.z + v.w * d.w;
    }
    as_o[n] = ss;
    ad_o[n] = dd;
}

// ---------------- CSR build ----------------
__global__ __launch_bounds__(256) void k_hist(const int* __restrict__ ei,
                                              int* __restrict__ deg)
{
    int e = blockIdx.x * blockDim.x + threadIdx.x;
    if (e >= ETOT) return;
    int dst = (e < EE) ? ei[EE + e] : (e - EE);
    atomicAdd(&deg[dst], 1);
}

__global__ __launch_bounds__(1024) void k_scan(const int* __restrict__ deg,
                                               int* __restrict__ row_ptr,
                                               int* __restrict__ cursor)
{
    __shared__ int sm[1024];
    __shared__ int carry;
    int tid = threadIdx.x;
    if (tid == 0) carry = 0;
    __syncthreads();
    for (int base = 0; base < NN; base += 8192) {
        int v[8];
        int s = 0;
        int i0 = base + tid * 8;
        #pragma unroll
        for (int j = 0; j < 8; ++j) {
            int i = i0 + j;
            v[j] = (i < NN) ? deg[i] : 0;
            s += v[j];
        }
        sm[tid] = s;
        __syncthreads();
        for (int ofs = 1; ofs < 1024; ofs <<= 1) {
            int t = (tid >= ofs) ? sm[tid - ofs] : 0;
            __syncthreads();
            sm[tid] += t;
            __syncthreads();
        }
        int excl = sm[tid] - s + carry;
        #pragma unroll
        for (int j = 0; j < 8; ++j) {
            int i = i0 + j;
            if (i < NN) { row_ptr[i] = excl; cursor[i] = excl; }
            excl += v[j];
        }
        int total = sm[1023];
        __syncthreads();
        if (tid == 0) carry += total;
        __syncthreads();
    }
    if (tid == 0) row_ptr[NN] = carry;   // == ETOT
}

__global__ __launch_bounds__(256) void k_scatter(const int* __restrict__ ei,
                                                 int* __restrict__ cursor,
                                                 int* __restrict__ csr_src)
{
    int e = blockIdx.x * blockDim.x + threadIdx.x;
    if (e >= ETOT) return;
    int src, dst;
    if (e < EE) { src = ei[e]; dst = ei[EE + e]; }
    else        { src = dst = e - EE; }
    int pos = atomicAdd(&cursor[dst], 1);
    csr_src[pos] = src;
}

// ---------------- pull aggregation, fused softmax-norm + bias + BN + ELU -> bf16 ----------------
// one wave per node; lane owns channels (lane) and (64+lane)
__global__ __launch_bounds__(256) void k_agg(const int* __restrict__ row_ptr,
                                             const int* __restrict__ csr_src,
                                             const float* __restrict__ h,
                                             const float* __restrict__ as,
                                             const float* __restrict__ ad,
                                             const float* __restrict__ b,
                                             const float* __restrict__ g,
                                             const float* __restrict__ be,
                                             const float* __restrict__ rm,
                                             const float* __restrict__ rv,
                                             short* __restrict__ out)
{
    int n = blockIdx.x * 4 + (threadIdx.x >> 6);
    if (n >= NN) return;
    int lane = threadIdx.x & 63;
    int hh0 = lane >> 4;                 // head of channel `lane` (0..3); channel 64+lane -> hh0+4
    float adv0 = ad[n * NH + hh0];
    float adv1 = ad[n * NH + hh0 + 4];
    float acc0 = 0.f, acc1 = 0.f, sw0 = 0.f, sw1 = 0.f;
    int jb = row_ptr[n], je = row_ptr[n + 1];
    for (int j = jb; j < je; ++j) {
        int src = csr_src[j];
        float l0 = as[src * NH + hh0] + adv0;
        float l1 = as[src * NH + hh0 + 4] + adv1;
        l0 = l0 > 0.f ? l0 : NEG_SLOPE * l0;
        l1 = l1 > 0.f ? l1 : NEG_SLOPE * l1;
        float w0 = __expf(l0);
        float w1 = __expf(l1);
        sw0 += w0; sw1 += w1;
        acc0 += w0 * h[(size_t)src * HCH + lane];
        acc1 += w1 * h[(size_t)src * HCH + 64 + lane];
    }
    int c0 = lane, c1 = 64 + lane;
    float r0 = acc0 / (sw0 + 1e-16f) + b[c0];
    float r1 = acc1 / (sw1 + 1e-16f) + b[c1];
    r0 = (r0 - rm[c0]) * (g[c0] * rsqrtf(rv[c0] + BN_EPS)) + be[c0];
    r1 = (r1 - rm[c1]) * (g[c1] * rsqrtf(rv[c1] + BN_EPS)) + be[c1];
    r0 = r0 > 0.f ? r0 : ELU_A * expm1f(r0);
    r1 = r1 > 0.f ? r1 : ELU_A * expm1f(r1);
    out[(size_t)n * HCH + c0] = f2b(r0);
    out[(size_t)n * HCH + c1] = f2b(r1);
}

// layer-2: 1 head, 40 channels, +bias only, fp32 straight to d_out
__global__ __launch_bounds__(256) void k_agg2(const int* __restrict__ row_ptr,
                                              const int* __restrict__ csr_src,
                                              const float* __restrict__ h2,
                                              const float* __restrict__ as,
                                              const float* __restrict__ ad,
                                              const float* __restrict__ b,
                                              float* __restrict__ out)
{
    int n = blockIdx.x * 4 + (threadIdx.x >> 6);
    if (n >= NN) return;
    int lane = threadIdx.x & 63;
    float adv = ad[n];
    float acc = 0.f, sw = 0.f;
    int jb = row_ptr[n], je = row_ptr[n + 1];
    for (int j = jb; j < je; ++j) {
        int src = csr_src[j];
        float l = as[src] + adv;
        l = l > 0.f ? l : NEG_SLOPE * l;
        float w = __expf(l);
        sw += w;
        if (lane < NLBL) acc += w * h2[(size_t)src * NLBL + lane];
    }
    if (lane < NLBL) out[(size_t)n * NLBL + lane] = acc / (sw + 1e-16f) + b[lane];
}

extern "C" void kernel_launch(void* const* d_in, const int* in_sizes, int n_in,
                              void* d_out, int out_size, void* d_ws, size_t ws_size,
                              hipStream_t stream)
{
    const float* x   = (const float*)d_in[0];
    const int*   ei  = (const int*)d_in[1];
    const float* W0  = (const float*)d_in[2];
    const float* as0 = (const float*)d_in[3];
    const float* ad0 = (const float*)d_in[4];
    const float* b0  = (const float*)d_in[5];
    const float* g0  = (const float*)d_in[6];
    const float* be0 = (const float*)d_in[7];
    const float* rm0 = (const float*)d_in[8];
    const float* rv0 = (const float*)d_in[9];
    const float* W1  = (const float*)d_in[10];
    const float* as1 = (const float*)d_in[11];
    const float* ad1 = (const float*)d_in[12];
    const float* b1  = (const float*)d_in[13];
    const float* g1  = (const float*)d_in[14];
    const float* be1 = (const float*)d_in[15];
    const float* rm1 = (const float*)d_in[16];
    const float* rv1 = (const float*)d_in[17];
    const float* W2  = (const float*)d_in[18];
    const float* a_s2 = (const float*)d_in[19];
    const float* a_d2 = (const float*)d_in[20];
    const float* b2  = (const float*)d_in[21];
    float* out = (float*)d_out;

    char* ws = (char*)d_ws;
    size_t off = 0;
    auto alloc = [&](size_t bytes) {
        void* p = (void*)(ws + off);
        off += (bytes + 255) & ~(size_t)255;
        return p;
    };
    float* hbuf   = (float*)alloc((size_t)NN * HCH * 4);   // fp32 GEMM out / gather source
    short* fbuf   = (short*)alloc((size_t)NN * HCH * 2);   // bf16 aggregated features (GEMM A input)
    float* asb    = (float*)alloc((size_t)NN * NH * 4);
    float* adb    = (float*)alloc((size_t)NN * NH * 4);
    int*   deg    = (int*)alloc((size_t)NN * 4);
    int*   rowp   = (int*)alloc((size_t)(NN + 1) * 4);
    int*   cursor = (int*)alloc((size_t)NN * 4);
    int*   csrs   = (int*)alloc((size_t)ETOT * 4);
    short* Wt0    = (short*)alloc((size_t)HCH * FIN * 2);
    short* Wt1    = (short*)alloc((size_t)HCH * HCH * 2);
    short* Wt2    = (short*)alloc((size_t)NLBLP * HCH * 2);
    float* h2     = hbuf;   // reuse: hbuf dead by layer 2

    const int T = 256;
    const int gE  = (ETOT + T - 1) / T;
    const int gNH = (NN * NH + T - 1) / T;
    const int gN4 = (NN + 3) / 4;
    const int gM  = (NN + 63) / 64;

    // ---------- weight prep ----------
    k_convW<<<(HCH * FIN + T - 1) / T, T, 0, stream>>>(W0, Wt0, FIN, HCH, HCH);
    k_convW<<<(HCH * HCH + T - 1) / T, T, 0, stream>>>(W1, Wt1, HCH, HCH, HCH);
    k_convW<<<(NLBLP * HCH + T - 1) / T, T, 0, stream>>>(W2, Wt2, HCH, NLBL, NLBLP);

    // ---------- CSR build (reused by all 3 layers) ----------
    hipMemsetAsync(deg, 0, (size_t)NN * 4, stream);
    k_hist<<<gE, T, 0, stream>>>(ei, deg);
    k_scan<<<1, 1024, 0, stream>>>(deg, rowp, cursor);
    k_scatter<<<gE, T, 0, stream>>>(ei, cursor, csrs);

    // ---------- layer 0 ----------
    k_gemm_mfma<FIN, 8, false><<<gM, T, 0, stream>>>(x, Wt0, hbuf, NN, HCH);
    k_alpha<<<gNH, T, 0, stream>>>(hbuf, as0, ad0, asb, adb);
    k_agg<<<gN4, T, 0, stream>>>(rowp, csrs, hbuf, asb, adb, b0, g0, be0, rm0, rv0, fbuf);

    // ---------- layer 1 ----------
    k_gemm_mfma<HCH, 8, true><<<gM, T, 0, stream>>>(fbuf, Wt1, hbuf, NN, HCH);
    k_alpha<<<gNH, T, 0, stream>>>(hbuf, as1, ad1, asb, adb);
    k_agg<<<gN4, T, 0, stream>>>(rowp, csrs, hbuf, asb, adb, b1, g1, be1, rm1, rv1, fbuf);

    // ---------- layer 2 ----------
    k_gemm_mfma<HCH, 3, true><<<gM, T, 0, stream>>>(fbuf, Wt2, h2, NN, NLBL);
    k_alpha2<<<(NN + T - 1) / T, T, 0, stream>>>(h2, a_s2, a_d2, asb, adb);
    k_agg2<<<gN4, T, 0, stream>>>(rowp, csrs, h2, asb, adb, b2, out);
}

// Round 4
// 589.352 us; speedup vs baseline: 22.3671x; 1.2207x over previous
//
#include <hip/hip_runtime.h>
#include <hip/hip_bf16.h>
#include <cstdint>
#include <cstddef>

#define NN 50000
#define EE 800000
#define FIN 512
#define HIDC 16
#define NH 8
#define HCH 128
#define NLBL 40
#define NLBLP 48
#define ETOT (EE + NN)
#define NEG_SLOPE 0.2f
#define ELU_A 0.2f
#define BN_EPS 1e-5f

typedef __attribute__((ext_vector_type(8))) short bf16x8;
typedef __attribute__((ext_vector_type(4))) float f32x4;

__device__ inline short f2b(float f) {
    __hip_bfloat16 h = __float2bfloat16(f);   // RNE
    return *reinterpret_cast<short*>(&h);
}
__device__ inline float blo(unsigned int u) {
    union { unsigned int u; float f; } v; v.u = u << 16; return v.f;
}
__device__ inline float bhi(unsigned int u) {
    union { unsigned int u; float f; } v; v.u = u & 0xffff0000u; return v.f;
}

// ---------------- weight transpose + bf16 convert: Wt[n][k] = bf16(W[k][n]) ----------------
__global__ __launch_bounds__(256) void k_convW(const float* __restrict__ W,
                                               short* __restrict__ Wt,
                                               int K, int N, int Np)
{
    int idx = blockIdx.x * blockDim.x + threadIdx.x;
    if (idx >= Np * K) return;
    int n = idx / K, k = idx - n * K;
    float v = (n < N) ? W[(size_t)k * N + n] : 0.f;
    Wt[idx] = f2b(v);
}

// ---------------- MFMA GEMM: C[M,N] = A[M,K] @ Wt^T, per-wave 16xN strip, bf16 out ----------------
template<int KDIM, int NTILES, bool A_BF16>
__global__ __launch_bounds__(256) void k_gemm_mfma(const void* __restrict__ Ap,
                                                   const short* __restrict__ Wt,
                                                   short* __restrict__ C,
                                                   int M, int N)
{
    const int wave = threadIdx.x >> 6;
    const int lane = threadIdx.x & 63;
    const int quad = lane >> 4;
    const int col  = lane & 15;
    int row = blockIdx.x * 64 + wave * 16 + col;
    int arow = row < M ? row : M - 1;

    f32x4 acc[NTILES];
    #pragma unroll
    for (int t = 0; t < NTILES; ++t) acc[t] = (f32x4){0.f, 0.f, 0.f, 0.f};

    #pragma unroll
    for (int k0 = 0; k0 < KDIM; k0 += 32) {
        bf16x8 afrag;
        if (A_BF16) {
            const short* Ab = (const short*)Ap;
            afrag = *(const bf16x8*)(Ab + (size_t)arow * KDIM + k0 + quad * 8);
        } else {
            const float* Af = (const float*)Ap;
            const float4* p = (const float4*)(Af + (size_t)arow * KDIM + k0 + quad * 8);
            float4 v0 = p[0], v1 = p[1];
            afrag[0] = f2b(v0.x); afrag[1] = f2b(v0.y);
            afrag[2] = f2b(v0.z); afrag[3] = f2b(v0.w);
            afrag[4] = f2b(v1.x); afrag[5] = f2b(v1.y);
            afrag[6] = f2b(v1.z); afrag[7] = f2b(v1.w);
        }
        #pragma unroll
        for (int t = 0; t < NTILES; ++t) {
            bf16x8 bfrag = *(const bf16x8*)(Wt + (size_t)(t * 16 + col) * KDIM + k0 + quad * 8);
            acc[t] = __builtin_amdgcn_mfma_f32_16x16x32_bf16(afrag, bfrag, acc[t], 0, 0, 0);
        }
    }

    int mbase = blockIdx.x * 64 + wave * 16 + quad * 4;
    #pragma unroll
    for (int t = 0; t < NTILES; ++t) {
        int c = t * 16 + col;
        if (c < N) {
            #pragma unroll
            for (int r = 0; r < 4; ++r) {
                int m = mbase + r;
                if (m < M) C[(size_t)m * N + c] = f2b(acc[t][r]);
            }
        }
    }
}

// ---------------- per-(node,head) attention logits from bf16 h ----------------
__global__ __launch_bounds__(256) void k_alpha(const unsigned short* __restrict__ h,
                                               const float* __restrict__ a_s,
                                               const float* __restrict__ a_d,
                                               float* __restrict__ as_o,
                                               float* __restrict__ ad_o)
{
    int idx = blockIdx.x * blockDim.x + threadIdx.x;   // n*NH + hh
    if (idx >= NN * NH) return;
    int hh = idx & (NH - 1);
    const uint4* hp = (const uint4*)(h + (size_t)idx * HIDC);
    uint4 q0 = hp[0], q1 = hp[1];
    unsigned int u[8] = {q0.x, q0.y, q0.z, q0.w, q1.x, q1.y, q1.z, q1.w};
    const float* ap = a_s + hh * HIDC;
    const float* dp = a_d + hh * HIDC;
    float ss = 0.f, dd = 0.f;
    #pragma unroll
    for (int i = 0; i < 8; ++i) {
        float f0 = blo(u[i]), f1 = bhi(u[i]);
        ss += f0 * ap[2 * i] + f1 * ap[2 * i + 1];
        dd += f0 * dp[2 * i] + f1 * dp[2 * i + 1];
    }
    as_o[idx] = ss;
    ad_o[idx] = dd;
}

__global__ __launch_bounds__(256) void k_alpha2(const unsigned short* __restrict__ h2,
                                                const float* __restrict__ a_s,
                                                const float* __restrict__ a_d,
                                                float* __restrict__ as_o,
                                                float* __restrict__ ad_o)
{
    int n = blockIdx.x * blockDim.x + threadIdx.x;
    if (n >= NN) return;
    const uint4* hp = (const uint4*)(h2 + (size_t)n * NLBL);
    float ss = 0.f, dd = 0.f;
    #pragma unroll
    for (int qi = 0; qi < 5; ++qi) {
        uint4 q = hp[qi];
        unsigned int u[4] = {q.x, q.y, q.z, q.w};
        #pragma unroll
        for (int j = 0; j < 4; ++j) {
            int c = qi * 8 + j * 2;
            float f0 = blo(u[j]), f1 = bhi(u[j]);
            ss += f0 * a_s[c] + f1 * a_s[c + 1];
            dd += f0 * a_d[c] + f1 * a_d[c + 1];
        }
    }
    as_o[n] = ss;
    ad_o[n] = dd;
}

// ---------------- CSR build ----------------
__global__ __launch_bounds__(256) void k_hist(const int* __restrict__ ei,
                                              int* __restrict__ deg)
{
    int e = blockIdx.x * blockDim.x + threadIdx.x;
    if (e >= ETOT) return;
    int dst = (e < EE) ? ei[EE + e] : (e - EE);
    atomicAdd(&deg[dst], 1);
}

__global__ __launch_bounds__(1024) void k_scan(const int* __restrict__ deg,
                                               int* __restrict__ row_ptr,
                                               int* __restrict__ cursor)
{
    __shared__ int sm[1024];
    __shared__ int carry;
    int tid = threadIdx.x;
    if (tid == 0) carry = 0;
    __syncthreads();
    for (int base = 0; base < NN; base += 8192) {
        int v[8];
        int s = 0;
        int i0 = base + tid * 8;
        #pragma unroll
        for (int j = 0; j < 8; ++j) {
            int i = i0 + j;
            v[j] = (i < NN) ? deg[i] : 0;
            s += v[j];
        }
        sm[tid] = s;
        __syncthreads();
        for (int ofs = 1; ofs < 1024; ofs <<= 1) {
            int t = (tid >= ofs) ? sm[tid - ofs] : 0;
            __syncthreads();
            sm[tid] += t;
            __syncthreads();
        }
        int excl = sm[tid] - s + carry;
        #pragma unroll
        for (int j = 0; j < 8; ++j) {
            int i = i0 + j;
            if (i < NN) { row_ptr[i] = excl; cursor[i] = excl; }
            excl += v[j];
        }
        int total = sm[1023];
        __syncthreads();
        if (tid == 0) carry += total;
        __syncthreads();
    }
    if (tid == 0) row_ptr[NN] = carry;   // == ETOT
}

__global__ __launch_bounds__(256) void k_scatter(const int* __restrict__ ei,
                                                 int* __restrict__ cursor,
                                                 int* __restrict__ csr_src)
{
    int e = blockIdx.x * blockDim.x + threadIdx.x;
    if (e >= ETOT) return;
    int src, dst;
    if (e < EE) { src = ei[e]; dst = ei[EE + e]; }
    else        { src = dst = e - EE; }
    int pos = atomicAdd(&cursor[dst], 1);
    csr_src[pos] = src;
}

// ---------------- pull aggregation (bf16 gather), fused softmax+bias+BN+ELU -> bf16 ----------------
// one wave per node; lane owns channel pair (2*lane, 2*lane+1); 2-edge unroll
__global__ __launch_bounds__(256) void k_agg(const int* __restrict__ row_ptr,
                                             const int* __restrict__ csr_src,
                                             const unsigned short* __restrict__ h,
                                             const float* __restrict__ as,
                                             const float* __restrict__ ad,
                                             const float* __restrict__ b,
                                             const float* __restrict__ g,
                                             const float* __restrict__ be,
                                             const float* __restrict__ rm,
                                             const float* __restrict__ rv,
                                             short* __restrict__ out)
{
    int n = blockIdx.x * 4 + (threadIdx.x >> 6);
    if (n >= NN) return;
    int lane = threadIdx.x & 63;
    int hh = lane >> 3;                  // head of channel 2*lane (both channels same head)
    float adv = ad[n * NH + hh];
    float acc0 = 0.f, acc1 = 0.f, sw = 0.f;
    int jb = row_ptr[n], je = row_ptr[n + 1];
    int j = jb;
    for (; j + 1 < je; j += 2) {
        int s0 = csr_src[j], s1 = csr_src[j + 1];
        float l0 = as[s0 * NH + hh] + adv;
        float l1 = as[s1 * NH + hh] + adv;
        unsigned int u0 = *(const unsigned int*)(h + (size_t)s0 * HCH + 2 * lane);
        unsigned int u1 = *(const unsigned int*)(h + (size_t)s1 * HCH + 2 * lane);
        l0 = l0 > 0.f ? l0 : NEG_SLOPE * l0;
        l1 = l1 > 0.f ? l1 : NEG_SLOPE * l1;
        float w0 = __expf(l0), w1 = __expf(l1);
        sw += w0 + w1;
        acc0 += w0 * blo(u0) + w1 * blo(u1);
        acc1 += w0 * bhi(u0) + w1 * bhi(u1);
    }
    if (j < je) {
        int s0 = csr_src[j];
        float l0 = as[s0 * NH + hh] + adv;
        unsigned int u0 = *(const unsigned int*)(h + (size_t)s0 * HCH + 2 * lane);
        l0 = l0 > 0.f ? l0 : NEG_SLOPE * l0;
        float w0 = __expf(l0);
        sw += w0;
        acc0 += w0 * blo(u0);
        acc1 += w0 * bhi(u0);
    }
    int c0 = 2 * lane, c1 = c0 + 1;
    float inv = 1.f / (sw + 1e-16f);
    float r0 = acc0 * inv + b[c0];
    float r1 = acc1 * inv + b[c1];
    r0 = (r0 - rm[c0]) * (g[c0] * rsqrtf(rv[c0] + BN_EPS)) + be[c0];
    r1 = (r1 - rm[c1]) * (g[c1] * rsqrtf(rv[c1] + BN_EPS)) + be[c1];
    r0 = r0 > 0.f ? r0 : ELU_A * expm1f(r0);
    r1 = r1 > 0.f ? r1 : ELU_A * expm1f(r1);
    out[(size_t)n * HCH + c0] = f2b(r0);
    out[(size_t)n * HCH + c1] = f2b(r1);
}

// layer-2: 1 head, 40 ch bf16 gather, 2 edges per wave (half-waves), fp32 out
__global__ __launch_bounds__(256) void k_agg2(const int* __restrict__ row_ptr,
                                              const int* __restrict__ csr_src,
                                              const unsigned short* __restrict__ h2,
                                              const float* __restrict__ as,
                                              const float* __restrict__ ad,
                                              const float* __restrict__ b,
                                              float* __restrict__ out)
{
    int n = blockIdx.x * 4 + (threadIdx.x >> 6);
    if (n >= NN) return;
    int lane = threadIdx.x & 63;
    int half = lane >> 5;                // which edge of the pair
    int c2 = lane & 31;                  // channel-pair index; active if c2 < 20
    float adv = ad[n];
    float acc0 = 0.f, acc1 = 0.f, sw = 0.f;
    int jb = row_ptr[n], je = row_ptr[n + 1];
    for (int j = jb + half; j < je; j += 2) {
        int s = csr_src[j];
        float l = as[s] + adv;
        l = l > 0.f ? l : NEG_SLOPE * l;
        float w = __expf(l);
        sw += w;
        if (c2 < 20) {
            unsigned int u = *(const unsigned int*)(h2 + (size_t)s * NLBL + 2 * c2);
            acc0 += w * blo(u);
            acc1 += w * bhi(u);
        }
    }
    float acc0b = __shfl_down(acc0, 32);
    float acc1b = __shfl_down(acc1, 32);
    float swb   = __shfl_down(sw, 32);
    if (half == 0 && c2 < 20) {
        acc0 += acc0b; acc1 += acc1b; sw += swb;
        float inv = 1.f / (sw + 1e-16f);
        out[(size_t)n * NLBL + 2 * c2]     = acc0 * inv + b[2 * c2];
        out[(size_t)n * NLBL + 2 * c2 + 1] = acc1 * inv + b[2 * c2 + 1];
    }
}

extern "C" void kernel_launch(void* const* d_in, const int* in_sizes, int n_in,
                              void* d_out, int out_size, void* d_ws, size_t ws_size,
                              hipStream_t stream)
{
    const float* x   = (const float*)d_in[0];
    const int*   ei  = (const int*)d_in[1];
    const float* W0  = (const float*)d_in[2];
    const float* as0 = (const float*)d_in[3];
    const float* ad0 = (const float*)d_in[4];
    const float* b0  = (const float*)d_in[5];
    const float* g0  = (const float*)d_in[6];
    const float* be0 = (const float*)d_in[7];
    const float* rm0 = (const float*)d_in[8];
    const float* rv0 = (const float*)d_in[9];
    const float* W1  = (const float*)d_in[10];
    const float* as1 = (const float*)d_in[11];
    const float* ad1 = (const float*)d_in[12];
    const float* b1  = (const float*)d_in[13];
    const float* g1  = (const float*)d_in[14];
    const float* be1 = (const float*)d_in[15];
    const float* rm1 = (const float*)d_in[16];
    const float* rv1 = (const float*)d_in[17];
    const float* W2  = (const float*)d_in[18];
    const float* a_s2 = (const float*)d_in[19];
    const float* a_d2 = (const float*)d_in[20];
    const float* b2  = (const float*)d_in[21];
    float* out = (float*)d_out;

    char* ws = (char*)d_ws;
    size_t off = 0;
    auto alloc = [&](size_t bytes) {
        void* p = (void*)(ws + off);
        off += (bytes + 255) & ~(size_t)255;
        return p;
    };
    short* hbuf   = (short*)alloc((size_t)NN * HCH * 2);   // bf16 GEMM out / gather source
    short* fbuf   = (short*)alloc((size_t)NN * HCH * 2);   // bf16 aggregated features (GEMM A input)
    float* asb    = (float*)alloc((size_t)NN * NH * 4);
    float* adb    = (float*)alloc((size_t)NN * NH * 4);
    int*   deg    = (int*)alloc((size_t)NN * 4);
    int*   rowp   = (int*)alloc((size_t)(NN + 1) * 4);
    int*   cursor = (int*)alloc((size_t)NN * 4);
    int*   csrs   = (int*)alloc((size_t)ETOT * 4);
    short* Wt0    = (short*)alloc((size_t)HCH * FIN * 2);
    short* Wt1    = (short*)alloc((size_t)HCH * HCH * 2);
    short* Wt2    = (short*)alloc((size_t)NLBLP * HCH * 2);
    short* h2     = hbuf;   // reuse: hbuf dead by layer 2

    const int T = 256;
    const int gE  = (ETOT + T - 1) / T;
    const int gNH = (NN * NH + T - 1) / T;
    const int gN4 = (NN + 3) / 4;
    const int gM  = (NN + 63) / 64;

    // ---------- weight prep ----------
    k_convW<<<(HCH * FIN + T - 1) / T, T, 0, stream>>>(W0, Wt0, FIN, HCH, HCH);
    k_convW<<<(HCH * HCH + T - 1) / T, T, 0, stream>>>(W1, Wt1, HCH, HCH, HCH);
    k_convW<<<(NLBLP * HCH + T - 1) / T, T, 0, stream>>>(W2, Wt2, HCH, NLBL, NLBLP);

    // ---------- CSR build (reused by all 3 layers) ----------
    hipMemsetAsync(deg, 0, (size_t)NN * 4, stream);
    k_hist<<<gE, T, 0, stream>>>(ei, deg);
    k_scan<<<1, 1024, 0, stream>>>(deg, rowp, cursor);
    k_scatter<<<gE, T, 0, stream>>>(ei, cursor, csrs);

    // ---------- layer 0 ----------
    k_gemm_mfma<FIN, 8, false><<<gM, T, 0, stream>>>(x, Wt0, hbuf, NN, HCH);
    k_alpha<<<gNH, T, 0, stream>>>((const unsigned short*)hbuf, as0, ad0, asb, adb);
    k_agg<<<gN4, T, 0, stream>>>(rowp, csrs, (const unsigned short*)hbuf, asb, adb,
                                 b0, g0, be0, rm0, rv0, fbuf);

    // ---------- layer 1 ----------
    k_gemm_mfma<HCH, 8, true><<<gM, T, 0, stream>>>(fbuf, Wt1, hbuf, NN, HCH);
    k_alpha<<<gNH, T, 0, stream>>>((const unsigned short*)hbuf, as1, ad1, asb, adb);
    k_agg<<<gN4, T, 0, stream>>>(rowp, csrs, (const unsigned short*)hbuf, asb, adb,
                                 b1, g1, be1, rm1, rv1, fbuf);

    // ---------- layer 2 ----------
    k_gemm_mfma<HCH, 3, true><<<gM, T, 0, stream>>>(fbuf, Wt2, h2, NN, NLBL);
    k_alpha2<<<(NN + T - 1) / T, T, 0, stream>>>((const unsigned short*)h2, a_s2, a_d2, asb, adb);
    k_agg2<<<gN4, T, 0, stream>>>(rowp, csrs, (const unsigned short*)h2, asb, adb, b2, out);
}

// Round 5
// 542.475 us; speedup vs baseline: 24.2999x; 1.0864x over previous
//
#include <hip/hip_runtime.h>
#include <hip/hip_bf16.h>
#include <cstdint>
#include <cstddef>

#define NN 50000
#define EE 800000
#define FIN 512
#define HIDC 16
#define NH 8
#define HCH 128
#define NLBL 40
#define NLBLP 48
#define ETOT (EE + NN)
#define NEG_SLOPE 0.2f
#define ELU_A 0.2f
#define BN_EPS 1e-5f

typedef __attribute__((ext_vector_type(8))) short bf16x8;
typedef __attribute__((ext_vector_type(4))) float f32x4;

__device__ inline short f2b(float f) {
    __hip_bfloat16 h = __float2bfloat16(f);   // RNE
    return *reinterpret_cast<short*>(&h);
}
__device__ inline float blo(unsigned int u) {
    union { unsigned int u; float f; } v; v.u = u << 16; return v.f;
}
__device__ inline float bhi(unsigned int u) {
    union { unsigned int u; float f; } v; v.u = u & 0xffff0000u; return v.f;
}

// ---------------- weight transpose + bf16 convert: Wt[n][k] = bf16(W[k][n]) ----------------
__global__ __launch_bounds__(256) void k_convW(const float* __restrict__ W,
                                               short* __restrict__ Wt,
                                               int K, int N, int Np)
{
    int idx = blockIdx.x * blockDim.x + threadIdx.x;
    if (idx >= Np * K) return;
    int n = idx / K, k = idx - n * K;
    float v = (n < N) ? W[(size_t)k * N + n] : 0.f;
    Wt[idx] = f2b(v);
}

// ---------------- MFMA GEMM, LDS-staged B + register-ring A prefetch ----------------
// C[M,N] = A[M,K] @ Wt^T, per-wave 16-row strip over full N.
// B chunk (NFULL x 128 k) staged in LDS (padded rows); A prefetched 4 ksteps deep.
template<int KDIM, int NTILES, bool A_BF16>
__global__ __launch_bounds__(256) void k_gemm_lds(const void* __restrict__ Ap,
                                                  const short* __restrict__ Wt,
                                                  short* __restrict__ C,
                                                  int M, int N)
{
    constexpr int NFULL = NTILES * 16;
    constexpr int KCH = 128;               // k-chunk
    constexpr int NK = KDIM / 32;          // total ksteps
    constexpr int NCH = KDIM / KCH;        // chunks
    constexpr int LROW = KCH + 8;          // shorts per LDS row (pad: +16B -> bank spread)
    __shared__ short Bs[NFULL * LROW];

    const int tid  = threadIdx.x;
    const int wave = tid >> 6;
    const int lane = tid & 63;
    const int quad = lane >> 4;
    const int col  = lane & 15;
    const int row  = blockIdx.x * 64 + wave * 16 + col;
    const int arow = row < M ? row : M - 1;

    f32x4 acc[NTILES];
    #pragma unroll
    for (int t = 0; t < NTILES; ++t) acc[t] = (f32x4){0.f, 0.f, 0.f, 0.f};

    // A prefetch ring (4 deep)
    bf16x8 arB[4];
    float4 arF[4][2];
    const short* Ab = (const short*)Ap;
    const float* Af = (const float*)Ap;
    auto pf = [&](int ks) {
        if (ks >= NK) return;
        if (A_BF16) {
            arB[ks & 3] = *(const bf16x8*)(Ab + (size_t)arow * KDIM + ks * 32 + quad * 8);
        } else {
            const float4* p = (const float4*)(Af + (size_t)arow * KDIM + ks * 32 + quad * 8);
            arF[ks & 3][0] = p[0];
            arF[ks & 3][1] = p[1];
        }
    };
    pf(0); pf(1); pf(2); pf(3);

    for (int c = 0; c < NCH; ++c) {
        // ---- stage B chunk c into LDS (coalesced 16B loads, padded ds_write) ----
        const int k0 = c * KCH;
        constexpr int TOT8 = NFULL * (KCH / 8);   // vec8 units; KCH/8 == 16
        #pragma unroll
        for (int i = tid; i < TOT8; i += 256) {
            int n  = i >> 4;
            int kk = i & 15;
            bf16x8 v = *(const bf16x8*)(Wt + (size_t)n * KDIM + k0 + kk * 8);
            *(bf16x8*)(Bs + n * LROW + kk * 8) = v;
        }
        __syncthreads();
        #pragma unroll
        for (int s = 0; s < KCH / 32; ++s) {
            const int ks = c * (KCH / 32) + s;
            bf16x8 afrag;
            if (A_BF16) {
                afrag = arB[ks & 3];
            } else {
                float4 v0 = arF[ks & 3][0], v1 = arF[ks & 3][1];
                afrag[0] = f2b(v0.x); afrag[1] = f2b(v0.y);
                afrag[2] = f2b(v0.z); afrag[3] = f2b(v0.w);
                afrag[4] = f2b(v1.x); afrag[5] = f2b(v1.y);
                afrag[6] = f2b(v1.z); afrag[7] = f2b(v1.w);
            }
            pf(ks + 4);
            #pragma unroll
            for (int t = 0; t < NTILES; ++t) {
                bf16x8 bfrag = *(const bf16x8*)(Bs + (t * 16 + col) * LROW + s * 32 + quad * 8);
                acc[t] = __builtin_amdgcn_mfma_f32_16x16x32_bf16(afrag, bfrag, acc[t], 0, 0, 0);
            }
        }
        if (c + 1 < NCH) __syncthreads();
    }

    const int mbase = blockIdx.x * 64 + wave * 16 + quad * 4;
    #pragma unroll
    for (int t = 0; t < NTILES; ++t) {
        int cc = t * 16 + col;
        if (cc < N) {
            #pragma unroll
            for (int r = 0; r < 4; ++r) {
                int m = mbase + r;
                if (m < M) C[(size_t)m * N + cc] = f2b(acc[t][r]);
            }
        }
    }
}

// ---------------- per-(node,head) attention logits from bf16 h ----------------
__global__ __launch_bounds__(256) void k_alpha(const unsigned short* __restrict__ h,
                                               const float* __restrict__ a_s,
                                               const float* __restrict__ a_d,
                                               float* __restrict__ as_o,
                                               float* __restrict__ ad_o)
{
    int idx = blockIdx.x * blockDim.x + threadIdx.x;   // n*NH + hh
    if (idx >= NN * NH) return;
    int hh = idx & (NH - 1);
    const uint4* hp = (const uint4*)(h + (size_t)idx * HIDC);
    uint4 q0 = hp[0], q1 = hp[1];
    unsigned int u[8] = {q0.x, q0.y, q0.z, q0.w, q1.x, q1.y, q1.z, q1.w};
    const float* ap = a_s + hh * HIDC;
    const float* dp = a_d + hh * HIDC;
    float ss = 0.f, dd = 0.f;
    #pragma unroll
    for (int i = 0; i < 8; ++i) {
        float f0 = blo(u[i]), f1 = bhi(u[i]);
        ss += f0 * ap[2 * i] + f1 * ap[2 * i + 1];
        dd += f0 * dp[2 * i] + f1 * dp[2 * i + 1];
    }
    as_o[idx] = ss;
    ad_o[idx] = dd;
}

__global__ __launch_bounds__(256) void k_alpha2(const unsigned short* __restrict__ h2,
                                                const float* __restrict__ a_s,
                                                const float* __restrict__ a_d,
                                                float* __restrict__ as_o,
                                                float* __restrict__ ad_o)
{
    int n = blockIdx.x * blockDim.x + threadIdx.x;
    if (n >= NN) return;
    const uint4* hp = (const uint4*)(h2 + (size_t)n * NLBL);
    float ss = 0.f, dd = 0.f;
    #pragma unroll
    for (int qi = 0; qi < 5; ++qi) {
        uint4 q = hp[qi];
        unsigned int u[4] = {q.x, q.y, q.z, q.w};
        #pragma unroll
        for (int j = 0; j < 4; ++j) {
            int c = qi * 8 + j * 2;
            float f0 = blo(u[j]), f1 = bhi(u[j]);
            ss += f0 * a_s[c] + f1 * a_s[c + 1];
            dd += f0 * a_d[c] + f1 * a_d[c + 1];
        }
    }
    as_o[n] = ss;
    ad_o[n] = dd;
}

// ---------------- CSR build ----------------
__global__ __launch_bounds__(256) void k_hist(const int* __restrict__ ei,
                                              int* __restrict__ deg)
{
    int e = blockIdx.x * blockDim.x + threadIdx.x;
    if (e >= ETOT) return;
    int dst = (e < EE) ? ei[EE + e] : (e - EE);
    atomicAdd(&deg[dst], 1);
}

__global__ __launch_bounds__(1024) void k_scan(const int* __restrict__ deg,
                                               int* __restrict__ row_ptr,
                                               int* __restrict__ cursor)
{
    __shared__ int sm[1024];
    __shared__ int carry;
    int tid = threadIdx.x;
    if (tid == 0) carry = 0;
    __syncthreads();
    for (int base = 0; base < NN; base += 8192) {
        int v[8];
        int s = 0;
        int i0 = base + tid * 8;
        #pragma unroll
        for (int j = 0; j < 8; ++j) {
            int i = i0 + j;
            v[j] = (i < NN) ? deg[i] : 0;
            s += v[j];
        }
        sm[tid] = s;
        __syncthreads();
        for (int ofs = 1; ofs < 1024; ofs <<= 1) {
            int t = (tid >= ofs) ? sm[tid - ofs] : 0;
            __syncthreads();
            sm[tid] += t;
            __syncthreads();
        }
        int excl = sm[tid] - s + carry;
        #pragma unroll
        for (int j = 0; j < 8; ++j) {
            int i = i0 + j;
            if (i < NN) { row_ptr[i] = excl; cursor[i] = excl; }
            excl += v[j];
        }
        int total = sm[1023];
        __syncthreads();
        if (tid == 0) carry += total;
        __syncthreads();
    }
    if (tid == 0) row_ptr[NN] = carry;   // == ETOT
}

__global__ __launch_bounds__(256) void k_scatter(const int* __restrict__ ei,
                                                 int* __restrict__ cursor,
                                                 int* __restrict__ csr_src)
{
    int e = blockIdx.x * blockDim.x + threadIdx.x;
    if (e >= ETOT) return;
    int src, dst;
    if (e < EE) { src = ei[e]; dst = ei[EE + e]; }
    else        { src = dst = e - EE; }
    int pos = atomicAdd(&cursor[dst], 1);
    csr_src[pos] = src;
}

// ---------------- pull aggregation (bf16 gather), fused softmax+bias+BN+ELU -> bf16 ----------------
__global__ __launch_bounds__(256) void k_agg(const int* __restrict__ row_ptr,
                                             const int* __restrict__ csr_src,
                                             const unsigned short* __restrict__ h,
                                             const float* __restrict__ as,
                                             const float* __restrict__ ad,
                                             const float* __restrict__ b,
                                             const float* __restrict__ g,
                                             const float* __restrict__ be,
                                             const float* __restrict__ rm,
                                             const float* __restrict__ rv,
                                             short* __restrict__ out)
{
    int n = blockIdx.x * 4 + (threadIdx.x >> 6);
    if (n >= NN) return;
    int lane = threadIdx.x & 63;
    int hh = lane >> 3;                  // head of channel 2*lane (both channels same head)
    float adv = ad[n * NH + hh];
    float acc0 = 0.f, acc1 = 0.f, sw = 0.f;
    int jb = row_ptr[n], je = row_ptr[n + 1];
    int j = jb;
    for (; j + 1 < je; j += 2) {
        int s0 = csr_src[j], s1 = csr_src[j + 1];
        float l0 = as[s0 * NH + hh] + adv;
        float l1 = as[s1 * NH + hh] + adv;
        unsigned int u0 = *(const unsigned int*)(h + (size_t)s0 * HCH + 2 * lane);
        unsigned int u1 = *(const unsigned int*)(h + (size_t)s1 * HCH + 2 * lane);
        l0 = l0 > 0.f ? l0 : NEG_SLOPE * l0;
        l1 = l1 > 0.f ? l1 : NEG_SLOPE * l1;
        float w0 = __expf(l0), w1 = __expf(l1);
        sw += w0 + w1;
        acc0 += w0 * blo(u0) + w1 * blo(u1);
        acc1 += w0 * bhi(u0) + w1 * bhi(u1);
    }
    if (j < je) {
        int s0 = csr_src[j];
        float l0 = as[s0 * NH + hh] + adv;
        unsigned int u0 = *(const unsigned int*)(h + (size_t)s0 * HCH + 2 * lane);
        l0 = l0 > 0.f ? l0 : NEG_SLOPE * l0;
        float w0 = __expf(l0);
        sw += w0;
        acc0 += w0 * blo(u0);
        acc1 += w0 * bhi(u0);
    }
    int c0 = 2 * lane, c1 = c0 + 1;
    float inv = 1.f / (sw + 1e-16f);
    float r0 = acc0 * inv + b[c0];
    float r1 = acc1 * inv + b[c1];
    r0 = (r0 - rm[c0]) * (g[c0] * rsqrtf(rv[c0] + BN_EPS)) + be[c0];
    r1 = (r1 - rm[c1]) * (g[c1] * rsqrtf(rv[c1] + BN_EPS)) + be[c1];
    r0 = r0 > 0.f ? r0 : ELU_A * expm1f(r0);
    r1 = r1 > 0.f ? r1 : ELU_A * expm1f(r1);
    out[(size_t)n * HCH + c0] = f2b(r0);
    out[(size_t)n * HCH + c1] = f2b(r1);
}

// layer-2: 1 head, 40 ch bf16 gather, 2 edges per wave (half-waves), fp32 out
__global__ __launch_bounds__(256) void k_agg2(const int* __restrict__ row_ptr,
                                              const int* __restrict__ csr_src,
                                              const unsigned short* __restrict__ h2,
                                              const float* __restrict__ as,
                                              const float* __restrict__ ad,
                                              const float* __restrict__ b,
                                              float* __restrict__ out)
{
    int n = blockIdx.x * 4 + (threadIdx.x >> 6);
    if (n >= NN) return;
    int lane = threadIdx.x & 63;
    int half = lane >> 5;                // which edge of the pair
    int c2 = lane & 31;                  // channel-pair index; active if c2 < 20
    float adv = ad[n];
    float acc0 = 0.f, acc1 = 0.f, sw = 0.f;
    int jb = row_ptr[n], je = row_ptr[n + 1];
    for (int j = jb + half; j < je; j += 2) {
        int s = csr_src[j];
        float l = as[s] + adv;
        l = l > 0.f ? l : NEG_SLOPE * l;
        float w = __expf(l);
        sw += w;
        if (c2 < 20) {
            unsigned int u = *(const unsigned int*)(h2 + (size_t)s * NLBL + 2 * c2);
            acc0 += w * blo(u);
            acc1 += w * bhi(u);
        }
    }
    float acc0b = __shfl_down(acc0, 32);
    float acc1b = __shfl_down(acc1, 32);
    float swb   = __shfl_down(sw, 32);
    if (half == 0 && c2 < 20) {
        acc0 += acc0b; acc1 += acc1b; sw += swb;
        float inv = 1.f / (sw + 1e-16f);
        out[(size_t)n * NLBL + 2 * c2]     = acc0 * inv + b[2 * c2];
        out[(size_t)n * NLBL + 2 * c2 + 1] = acc1 * inv + b[2 * c2 + 1];
    }
}

extern "C" void kernel_launch(void* const* d_in, const int* in_sizes, int n_in,
                              void* d_out, int out_size, void* d_ws, size_t ws_size,
                              hipStream_t stream)
{
    const float* x   = (const float*)d_in[0];
    const int*   ei  = (const int*)d_in[1];
    const float* W0  = (const float*)d_in[2];
    const float* as0 = (const float*)d_in[3];
    const float* ad0 = (const float*)d_in[4];
    const float* b0  = (const float*)d_in[5];
    const float* g0  = (const float*)d_in[6];
    const float* be0 = (const float*)d_in[7];
    const float* rm0 = (const float*)d_in[8];
    const float* rv0 = (const float*)d_in[9];
    const float* W1  = (const float*)d_in[10];
    const float* as1 = (const float*)d_in[11];
    const float* ad1 = (const float*)d_in[12];
    const float* b1  = (const float*)d_in[13];
    const float* g1  = (const float*)d_in[14];
    const float* be1 = (const float*)d_in[15];
    const float* rm1 = (const float*)d_in[16];
    const float* rv1 = (const float*)d_in[17];
    const float* W2  = (const float*)d_in[18];
    const float* a_s2 = (const float*)d_in[19];
    const float* a_d2 = (const float*)d_in[20];
    const float* b2  = (const float*)d_in[21];
    float* out = (float*)d_out;

    char* ws = (char*)d_ws;
    size_t off = 0;
    auto alloc = [&](size_t bytes) {
        void* p = (void*)(ws + off);
        off += (bytes + 255) & ~(size_t)255;
        return p;
    };
    short* hbuf   = (short*)alloc((size_t)NN * HCH * 2);   // bf16 GEMM out / gather source
    short* fbuf   = (short*)alloc((size_t)NN * HCH * 2);   // bf16 aggregated features (GEMM A input)
    float* asb    = (float*)alloc((size_t)NN * NH * 4);
    float* adb    = (float*)alloc((size_t)NN * NH * 4);
    int*   deg    = (int*)alloc((size_t)NN * 4);
    int*   rowp   = (int*)alloc((size_t)(NN + 1) * 4);
    int*   cursor = (int*)alloc((size_t)NN * 4);
    int*   csrs   = (int*)alloc((size_t)ETOT * 4);
    short* Wt0    = (short*)alloc((size_t)HCH * FIN * 2);
    short* Wt1    = (short*)alloc((size_t)HCH * HCH * 2);
    short* Wt2    = (short*)alloc((size_t)NLBLP * HCH * 2);
    short* h2     = hbuf;   // reuse: hbuf dead by layer 2

    const int T = 256;
    const int gE  = (ETOT + T - 1) / T;
    const int gNH = (NN * NH + T - 1) / T;
    const int gN4 = (NN + 3) / 4;
    const int gM  = (NN + 63) / 64;

    // ---------- weight prep ----------
    k_convW<<<(HCH * FIN + T - 1) / T, T, 0, stream>>>(W0, Wt0, FIN, HCH, HCH);
    k_convW<<<(HCH * HCH + T - 1) / T, T, 0, stream>>>(W1, Wt1, HCH, HCH, HCH);
    k_convW<<<(NLBLP * HCH + T - 1) / T, T, 0, stream>>>(W2, Wt2, HCH, NLBL, NLBLP);

    // ---------- CSR build (reused by all 3 layers) ----------
    hipMemsetAsync(deg, 0, (size_t)NN * 4, stream);
    k_hist<<<gE, T, 0, stream>>>(ei, deg);
    k_scan<<<1, 1024, 0, stream>>>(deg, rowp, cursor);
    k_scatter<<<gE, T, 0, stream>>>(ei, cursor, csrs);

    // ---------- layer 0 ----------
    k_gemm_lds<FIN, 8, false><<<gM, T, 0, stream>>>(x, Wt0, hbuf, NN, HCH);
    k_alpha<<<gNH, T, 0, stream>>>((const unsigned short*)hbuf, as0, ad0, asb, adb);
    k_agg<<<gN4, T, 0, stream>>>(rowp, csrs, (const unsigned short*)hbuf, asb, adb,
                                 b0, g0, be0, rm0, rv0, fbuf);

    // ---------- layer 1 ----------
    k_gemm_lds<HCH, 8, true><<<gM, T, 0, stream>>>(fbuf, Wt1, hbuf, NN, HCH);
    k_alpha<<<gNH, T, 0, stream>>>((const unsigned short*)hbuf, as1, ad1, asb, adb);
    k_agg<<<gN4, T, 0, stream>>>(rowp, csrs, (const unsigned short*)hbuf, asb, adb,
                                 b1, g1, be1, rm1, rv1, fbuf);

    // ---------- layer 2 ----------
    k_gemm_lds<HCH, 3, true><<<gM, T, 0, stream>>>(fbuf, Wt2, h2, NN, NLBL);
    k_alpha2<<<(NN + T - 1) / T, T, 0, stream>>>((const unsigned short*)h2, a_s2, a_d2, asb, adb);
    k_agg2<<<gN4, T, 0, stream>>>(rowp, csrs, (const unsigned short*)h2, asb, adb, b2, out);
}

// Round 6
// 509.349 us; speedup vs baseline: 25.8803x; 1.0650x over previous
//
#include <hip/hip_runtime.h>
#include <hip/hip_bf16.h>
#include <cstdint>
#include <cstddef>

#define NN 50000
#define EE 800000
#define FIN 512
#define HIDC 16
#define NH 8
#define HCH 128
#define NLBL 40
#define NLBLP 48
#define ETOT (EE + NN)
#define NEG_SLOPE 0.2f
#define ELU_A 0.2f
#define BN_EPS 1e-5f

typedef __attribute__((ext_vector_type(8))) short bf16x8;
typedef __attribute__((ext_vector_type(4))) float f32x4;

__device__ inline short f2b(float f) {
    __hip_bfloat16 h = __float2bfloat16(f);   // RNE
    return *reinterpret_cast<short*>(&h);
}
__device__ inline float blo(unsigned int u) {
    union { unsigned int u; float f; } v; v.u = u << 16; return v.f;
}
__device__ inline float bhi(unsigned int u) {
    union { unsigned int u; float f; } v; v.u = u & 0xffff0000u; return v.f;
}

// ---------------- weight transpose + bf16 convert: Wt[n][k] = bf16(W[k][n]) ----------------
__global__ __launch_bounds__(256) void k_convW(const float* __restrict__ W,
                                               short* __restrict__ Wt,
                                               int K, int N, int Np)
{
    int idx = blockIdx.x * blockDim.x + threadIdx.x;
    if (idx >= Np * K) return;
    int n = idx / K, k = idx - n * K;
    float v = (n < N) ? W[(size_t)k * N + n] : 0.f;
    Wt[idx] = f2b(v);
}

// ---------------- MFMA GEMM, LDS-staged B + register-ring A prefetch ----------------
template<int KDIM, int NTILES, bool A_BF16>
__global__ __launch_bounds__(256) void k_gemm_lds(const void* __restrict__ Ap,
                                                  const short* __restrict__ Wt,
                                                  short* __restrict__ C,
                                                  int M, int N)
{
    constexpr int NFULL = NTILES * 16;
    constexpr int KCH = 128;               // k-chunk
    constexpr int NK = KDIM / 32;          // total ksteps
    constexpr int NCH = KDIM / KCH;        // chunks
    constexpr int LROW = KCH + 8;          // shorts per LDS row
    __shared__ short Bs[NFULL * LROW];

    const int tid  = threadIdx.x;
    const int wave = tid >> 6;
    const int lane = tid & 63;
    const int quad = lane >> 4;
    const int col  = lane & 15;
    const int row  = blockIdx.x * 64 + wave * 16 + col;
    const int arow = row < M ? row : M - 1;

    f32x4 acc[NTILES];
    #pragma unroll
    for (int t = 0; t < NTILES; ++t) acc[t] = (f32x4){0.f, 0.f, 0.f, 0.f};

    bf16x8 arB[4];
    float4 arF[4][2];
    const short* Ab = (const short*)Ap;
    const float* Af = (const float*)Ap;
    auto pf = [&](int ks) {
        if (ks >= NK) return;
        if (A_BF16) {
            arB[ks & 3] = *(const bf16x8*)(Ab + (size_t)arow * KDIM + ks * 32 + quad * 8);
        } else {
            const float4* p = (const float4*)(Af + (size_t)arow * KDIM + ks * 32 + quad * 8);
            arF[ks & 3][0] = p[0];
            arF[ks & 3][1] = p[1];
        }
    };
    pf(0); pf(1); pf(2); pf(3);

    for (int c = 0; c < NCH; ++c) {
        const int k0 = c * KCH;
        constexpr int TOT8 = NFULL * (KCH / 8);
        #pragma unroll
        for (int i = tid; i < TOT8; i += 256) {
            int n  = i >> 4;
            int kk = i & 15;
            bf16x8 v = *(const bf16x8*)(Wt + (size_t)n * KDIM + k0 + kk * 8);
            *(bf16x8*)(Bs + n * LROW + kk * 8) = v;
        }
        __syncthreads();
        #pragma unroll
        for (int s = 0; s < KCH / 32; ++s) {
            const int ks = c * (KCH / 32) + s;
            bf16x8 afrag;
            if (A_BF16) {
                afrag = arB[ks & 3];
            } else {
                float4 v0 = arF[ks & 3][0], v1 = arF[ks & 3][1];
                afrag[0] = f2b(v0.x); afrag[1] = f2b(v0.y);
                afrag[2] = f2b(v0.z); afrag[3] = f2b(v0.w);
                afrag[4] = f2b(v1.x); afrag[5] = f2b(v1.y);
                afrag[6] = f2b(v1.z); afrag[7] = f2b(v1.w);
            }
            pf(ks + 4);
            #pragma unroll
            for (int t = 0; t < NTILES; ++t) {
                bf16x8 bfrag = *(const bf16x8*)(Bs + (t * 16 + col) * LROW + s * 32 + quad * 8);
                acc[t] = __builtin_amdgcn_mfma_f32_16x16x32_bf16(afrag, bfrag, acc[t], 0, 0, 0);
            }
        }
        if (c + 1 < NCH) __syncthreads();
    }

    const int mbase = blockIdx.x * 64 + wave * 16 + quad * 4;
    #pragma unroll
    for (int t = 0; t < NTILES; ++t) {
        int cc = t * 16 + col;
        if (cc < N) {
            #pragma unroll
            for (int r = 0; r < 4; ++r) {
                int m = mbase + r;
                if (m < M) C[(size_t)m * N + cc] = f2b(acc[t][r]);
            }
        }
    }
}

// ---------------- per-(node,head) attention logits from bf16 h ----------------
__global__ __launch_bounds__(256) void k_alpha(const unsigned short* __restrict__ h,
                                               const float* __restrict__ a_s,
                                               const float* __restrict__ a_d,
                                               float* __restrict__ as_o,
                                               float* __restrict__ ad_o)
{
    int idx = blockIdx.x * blockDim.x + threadIdx.x;   // n*NH + hh
    if (idx >= NN * NH) return;
    int hh = idx & (NH - 1);
    const uint4* hp = (const uint4*)(h + (size_t)idx * HIDC);
    uint4 q0 = hp[0], q1 = hp[1];
    unsigned int u[8] = {q0.x, q0.y, q0.z, q0.w, q1.x, q1.y, q1.z, q1.w};
    const float* ap = a_s + hh * HIDC;
    const float* dp = a_d + hh * HIDC;
    float ss = 0.f, dd = 0.f;
    #pragma unroll
    for (int i = 0; i < 8; ++i) {
        float f0 = blo(u[i]), f1 = bhi(u[i]);
        ss += f0 * ap[2 * i] + f1 * ap[2 * i + 1];
        dd += f0 * dp[2 * i] + f1 * dp[2 * i + 1];
    }
    as_o[idx] = ss;
    ad_o[idx] = dd;
}

__global__ __launch_bounds__(256) void k_alpha2(const unsigned short* __restrict__ h2,
                                                const float* __restrict__ a_s,
                                                const float* __restrict__ a_d,
                                                float* __restrict__ as_o,
                                                float* __restrict__ ad_o)
{
    int n = blockIdx.x * blockDim.x + threadIdx.x;
    if (n >= NN) return;
    const uint4* hp = (const uint4*)(h2 + (size_t)n * NLBL);
    float ss = 0.f, dd = 0.f;
    #pragma unroll
    for (int qi = 0; qi < 5; ++qi) {
        uint4 q = hp[qi];
        unsigned int u[4] = {q.x, q.y, q.z, q.w};
        #pragma unroll
        for (int j = 0; j < 4; ++j) {
            int c = qi * 8 + j * 2;
            float f0 = blo(u[j]), f1 = bhi(u[j]);
            ss += f0 * a_s[c] + f1 * a_s[c + 1];
            dd += f0 * a_d[c] + f1 * a_d[c + 1];
        }
    }
    as_o[n] = ss;
    ad_o[n] = dd;
}

// ---------------- CSR build ----------------
__global__ __launch_bounds__(256) void k_hist(const int* __restrict__ ei,
                                              int* __restrict__ deg)
{
    int e = blockIdx.x * blockDim.x + threadIdx.x;
    if (e >= ETOT) return;
    int dst = (e < EE) ? ei[EE + e] : (e - EE);
    atomicAdd(&deg[dst], 1);
}

__global__ __launch_bounds__(1024) void k_scan(const int* __restrict__ deg,
                                               int* __restrict__ row_ptr,
                                               int* __restrict__ cursor)
{
    __shared__ int sm[1024];
    __shared__ int carry;
    int tid = threadIdx.x;
    if (tid == 0) carry = 0;
    __syncthreads();
    for (int base = 0; base < NN; base += 8192) {
        int v[8];
        int s = 0;
        int i0 = base + tid * 8;
        #pragma unroll
        for (int j = 0; j < 8; ++j) {
            int i = i0 + j;
            v[j] = (i < NN) ? deg[i] : 0;
            s += v[j];
        }
        sm[tid] = s;
        __syncthreads();
        for (int ofs = 1; ofs < 1024; ofs <<= 1) {
            int t = (tid >= ofs) ? sm[tid - ofs] : 0;
            __syncthreads();
            sm[tid] += t;
            __syncthreads();
        }
        int excl = sm[tid] - s + carry;
        #pragma unroll
        for (int j = 0; j < 8; ++j) {
            int i = i0 + j;
            if (i < NN) { row_ptr[i] = excl; cursor[i] = excl; }
            excl += v[j];
        }
        int total = sm[1023];
        __syncthreads();
        if (tid == 0) carry += total;
        __syncthreads();
    }
    if (tid == 0) row_ptr[NN] = carry;   // == ETOT
}

__global__ __launch_bounds__(256) void k_scatter(const int* __restrict__ ei,
                                                 int* __restrict__ cursor,
                                                 int* __restrict__ csr_src)
{
    int e = blockIdx.x * blockDim.x + threadIdx.x;
    if (e >= ETOT) return;
    int src, dst;
    if (e < EE) { src = ei[e]; dst = ei[EE + e]; }
    else        { src = dst = e - EE; }
    int pos = atomicAdd(&cursor[dst], 1);
    csr_src[pos] = src;
}

// ---------------- pull aggregation: half-wave per edge, lane owns 4 channels ----------------
// wave = 1 node; half-waves process alternating edges (2-deep unroll -> 4 gathers in flight);
// __shfl_down(32) combine; fused softmax-norm + bias + BN + ELU -> packed bf16 store.
__global__ __launch_bounds__(256) void k_agg(const int* __restrict__ row_ptr,
                                             const int* __restrict__ csr_src,
                                             const unsigned short* __restrict__ h,
                                             const float* __restrict__ as,
                                             const float* __restrict__ ad,
                                             const float* __restrict__ b,
                                             const float* __restrict__ g,
                                             const float* __restrict__ be,
                                             const float* __restrict__ rm,
                                             const float* __restrict__ rv,
                                             short* __restrict__ out)
{
    int n = blockIdx.x * 4 + (threadIdx.x >> 6);
    if (n >= NN) return;
    int lane = threadIdx.x & 63;
    int half = lane >> 5;
    int c4 = lane & 31;                  // channel group: channels 4*c4 .. 4*c4+3
    int hh = c4 >> 2;                    // head (channels 4*c4.. within head c4/4)
    float adv = ad[n * NH + hh];
    float a0 = 0.f, a1 = 0.f, a2 = 0.f, a3 = 0.f, sw = 0.f;
    int jb = row_ptr[n], je = row_ptr[n + 1];
    int j = jb + half;
    for (; j + 2 < je; j += 4) {
        int s0 = csr_src[j], s1 = csr_src[j + 2];
        float l0 = as[s0 * NH + hh] + adv;
        float l1 = as[s1 * NH + hh] + adv;
        uint2 u0 = *(const uint2*)(h + (size_t)s0 * HCH + 4 * c4);
        uint2 u1 = *(const uint2*)(h + (size_t)s1 * HCH + 4 * c4);
        l0 = l0 > 0.f ? l0 : NEG_SLOPE * l0;
        l1 = l1 > 0.f ? l1 : NEG_SLOPE * l1;
        float w0 = __expf(l0), w1 = __expf(l1);
        sw += w0 + w1;
        a0 += w0 * blo(u0.x) + w1 * blo(u1.x);
        a1 += w0 * bhi(u0.x) + w1 * bhi(u1.x);
        a2 += w0 * blo(u0.y) + w1 * blo(u1.y);
        a3 += w0 * bhi(u0.y) + w1 * bhi(u1.y);
    }
    if (j < je) {
        int s0 = csr_src[j];
        float l0 = as[s0 * NH + hh] + adv;
        uint2 u0 = *(const uint2*)(h + (size_t)s0 * HCH + 4 * c4);
        l0 = l0 > 0.f ? l0 : NEG_SLOPE * l0;
        float w0 = __expf(l0);
        sw += w0;
        a0 += w0 * blo(u0.x);
        a1 += w0 * bhi(u0.x);
        a2 += w0 * blo(u0.y);
        a3 += w0 * bhi(u0.y);
    }
    // combine the two half-waves
    a0 += __shfl_down(a0, 32);
    a1 += __shfl_down(a1, 32);
    a2 += __shfl_down(a2, 32);
    a3 += __shfl_down(a3, 32);
    sw += __shfl_down(sw, 32);
    if (half == 0) {
        int c = 4 * c4;
        float inv = 1.f / (sw + 1e-16f);
        float4 bv  = *(const float4*)(b + c);
        float4 gv  = *(const float4*)(g + c);
        float4 bev = *(const float4*)(be + c);
        float4 rmv = *(const float4*)(rm + c);
        float4 rvv = *(const float4*)(rv + c);
        float r0 = a0 * inv + bv.x;
        float r1 = a1 * inv + bv.y;
        float r2 = a2 * inv + bv.z;
        float r3 = a3 * inv + bv.w;
        r0 = (r0 - rmv.x) * (gv.x * rsqrtf(rvv.x + BN_EPS)) + bev.x;
        r1 = (r1 - rmv.y) * (gv.y * rsqrtf(rvv.y + BN_EPS)) + bev.y;
        r2 = (r2 - rmv.z) * (gv.z * rsqrtf(rvv.z + BN_EPS)) + bev.z;
        r3 = (r3 - rmv.w) * (gv.w * rsqrtf(rvv.w + BN_EPS)) + bev.w;
        r0 = r0 > 0.f ? r0 : ELU_A * expm1f(r0);
        r1 = r1 > 0.f ? r1 : ELU_A * expm1f(r1);
        r2 = r2 > 0.f ? r2 : ELU_A * expm1f(r2);
        r3 = r3 > 0.f ? r3 : ELU_A * expm1f(r3);
        unsigned int lo = (unsigned int)(unsigned short)f2b(r0) |
                          ((unsigned int)(unsigned short)f2b(r1) << 16);
        unsigned int hi = (unsigned int)(unsigned short)f2b(r2) |
                          ((unsigned int)(unsigned short)f2b(r3) << 16);
        *(uint2*)(out + (size_t)n * HCH + c) = make_uint2(lo, hi);
    }
}

// layer-2: 1 head, 40 ch bf16 gather, 2 edges per wave (half-waves), fp32 out
__global__ __launch_bounds__(256) void k_agg2(const int* __restrict__ row_ptr,
                                              const int* __restrict__ csr_src,
                                              const unsigned short* __restrict__ h2,
                                              const float* __restrict__ as,
                                              const float* __restrict__ ad,
                                              const float* __restrict__ b,
                                              float* __restrict__ out)
{
    int n = blockIdx.x * 4 + (threadIdx.x >> 6);
    if (n >= NN) return;
    int lane = threadIdx.x & 63;
    int half = lane >> 5;                // which edge of the pair
    int c2 = lane & 31;                  // channel-pair index; active if c2 < 20
    float adv = ad[n];
    float acc0 = 0.f, acc1 = 0.f, sw = 0.f;
    int jb = row_ptr[n], je = row_ptr[n + 1];
    for (int j = jb + half; j < je; j += 2) {
        int s = csr_src[j];
        float l = as[s] + adv;
        l = l > 0.f ? l : NEG_SLOPE * l;
        float w = __expf(l);
        sw += w;
        if (c2 < 20) {
            unsigned int u = *(const unsigned int*)(h2 + (size_t)s * NLBL + 2 * c2);
            acc0 += w * blo(u);
            acc1 += w * bhi(u);
        }
    }
    float acc0b = __shfl_down(acc0, 32);
    float acc1b = __shfl_down(acc1, 32);
    float swb   = __shfl_down(sw, 32);
    if (half == 0 && c2 < 20) {
        acc0 += acc0b; acc1 += acc1b; sw += swb;
        float inv = 1.f / (sw + 1e-16f);
        out[(size_t)n * NLBL + 2 * c2]     = acc0 * inv + b[2 * c2];
        out[(size_t)n * NLBL + 2 * c2 + 1] = acc1 * inv + b[2 * c2 + 1];
    }
}

extern "C" void kernel_launch(void* const* d_in, const int* in_sizes, int n_in,
                              void* d_out, int out_size, void* d_ws, size_t ws_size,
                              hipStream_t stream)
{
    const float* x   = (const float*)d_in[0];
    const int*   ei  = (const int*)d_in[1];
    const float* W0  = (const float*)d_in[2];
    const float* as0 = (const float*)d_in[3];
    const float* ad0 = (const float*)d_in[4];
    const float* b0  = (const float*)d_in[5];
    const float* g0  = (const float*)d_in[6];
    const float* be0 = (const float*)d_in[7];
    const float* rm0 = (const float*)d_in[8];
    const float* rv0 = (const float*)d_in[9];
    const float* W1  = (const float*)d_in[10];
    const float* as1 = (const float*)d_in[11];
    const float* ad1 = (const float*)d_in[12];
    const float* b1  = (const float*)d_in[13];
    const float* g1  = (const float*)d_in[14];
    const float* be1 = (const float*)d_in[15];
    const float* rm1 = (const float*)d_in[16];
    const float* rv1 = (const float*)d_in[17];
    const float* W2  = (const float*)d_in[18];
    const float* a_s2 = (const float*)d_in[19];
    const float* a_d2 = (const float*)d_in[20];
    const float* b2  = (const float*)d_in[21];
    float* out = (float*)d_out;

    char* ws = (char*)d_ws;
    size_t off = 0;
    auto alloc = [&](size_t bytes) {
        void* p = (void*)(ws + off);
        off += (bytes + 255) & ~(size_t)255;
        return p;
    };
    short* hbuf   = (short*)alloc((size_t)NN * HCH * 2);   // bf16 GEMM out / gather source
    short* fbuf   = (short*)alloc((size_t)NN * HCH * 2);   // bf16 aggregated features (GEMM A input)
    float* asb    = (float*)alloc((size_t)NN * NH * 4);
    float* adb    = (float*)alloc((size_t)NN * NH * 4);
    int*   deg    = (int*)alloc((size_t)NN * 4);
    int*   rowp   = (int*)alloc((size_t)(NN + 1) * 4);
    int*   cursor = (int*)alloc((size_t)NN * 4);
    int*   csrs   = (int*)alloc((size_t)ETOT * 4);
    short* Wt0    = (short*)alloc((size_t)HCH * FIN * 2);
    short* Wt1    = (short*)alloc((size_t)HCH * HCH * 2);
    short* Wt2    = (short*)alloc((size_t)NLBLP * HCH * 2);
    short* h2     = hbuf;   // reuse: hbuf dead by layer 2

    const int T = 256;
    const int gE  = (ETOT + T - 1) / T;
    const int gNH = (NN * NH + T - 1) / T;
    const int gN4 = (NN + 3) / 4;
    const int gM  = (NN + 63) / 64;

    // ---------- weight prep ----------
    k_convW<<<(HCH * FIN + T - 1) / T, T, 0, stream>>>(W0, Wt0, FIN, HCH, HCH);
    k_convW<<<(HCH * HCH + T - 1) / T, T, 0, stream>>>(W1, Wt1, HCH, HCH, HCH);
    k_convW<<<(NLBLP * HCH + T - 1) / T, T, 0, stream>>>(W2, Wt2, HCH, NLBL, NLBLP);

    // ---------- CSR build (reused by all 3 layers) ----------
    hipMemsetAsync(deg, 0, (size_t)NN * 4, stream);
    k_hist<<<gE, T, 0, stream>>>(ei, deg);
    k_scan<<<1, 1024, 0, stream>>>(deg, rowp, cursor);
    k_scatter<<<gE, T, 0, stream>>>(ei, cursor, csrs);

    // ---------- layer 0 ----------
    k_gemm_lds<FIN, 8, false><<<gM, T, 0, stream>>>(x, Wt0, hbuf, NN, HCH);
    k_alpha<<<gNH, T, 0, stream>>>((const unsigned short*)hbuf, as0, ad0, asb, adb);
    k_agg<<<gN4, T, 0, stream>>>(rowp, csrs, (const unsigned short*)hbuf, asb, adb,
                                 b0, g0, be0, rm0, rv0, fbuf);

    // ---------- layer 1 ----------
    k_gemm_lds<HCH, 8, true><<<gM, T, 0, stream>>>(fbuf, Wt1, hbuf, NN, HCH);
    k_alpha<<<gNH, T, 0, stream>>>((const unsigned short*)hbuf, as1, ad1, asb, adb);
    k_agg<<<gN4, T, 0, stream>>>(rowp, csrs, (const unsigned short*)hbuf, asb, adb,
                                 b1, g1, be1, rm1, rv1, fbuf);

    // ---------- layer 2 ----------
    k_gemm_lds<HCH, 3, true><<<gM, T, 0, stream>>>(fbuf, Wt2, h2, NN, NLBL);
    k_alpha2<<<(NN + T - 1) / T, T, 0, stream>>>((const unsigned short*)h2, a_s2, a_d2, asb, adb);
    k_agg2<<<gN4, T, 0, stream>>>(rowp, csrs, (const unsigned short*)h2, asb, adb, b2, out);
}

// Round 7
// 478.425 us; speedup vs baseline: 27.5531x; 1.0646x over previous
//
#include <hip/hip_runtime.h>
#include <hip/hip_bf16.h>
#include <cstdint>
#include <cstddef>

#define NN 50000
#define EE 800000
#define FIN 512
#define HIDC 16
#define NH 8
#define HCH 128
#define NLBL 40
#define NLBLP 48
#define ETOT (EE + NN)
#define NEG_SLOPE 0.2f
#define ELU_A 0.2f
#define BN_EPS 1e-5f

typedef __attribute__((ext_vector_type(8))) short bf16x8;
typedef __attribute__((ext_vector_type(4))) float f32x4;

__device__ inline short f2b(float f) {
    __hip_bfloat16 h = __float2bfloat16(f);   // RNE
    return *reinterpret_cast<short*>(&h);
}
__device__ inline float blo(unsigned int u) {
    union { unsigned int u; float f; } v; v.u = u << 16; return v.f;
}
__device__ inline float bhi(unsigned int u) {
    union { unsigned int u; float f; } v; v.u = u & 0xffff0000u; return v.f;
}

// ---------------- weight transpose + bf16 convert: Wt[n][k] = bf16(W[k][n]) ----------------
__global__ __launch_bounds__(256) void k_convW(const float* __restrict__ W,
                                               short* __restrict__ Wt,
                                               int K, int N, int Np)
{
    int idx = blockIdx.x * blockDim.x + threadIdx.x;
    if (idx >= Np * K) return;
    int n = idx / K, k = idx - n * K;
    float v = (n < N) ? W[(size_t)k * N + n] : 0.f;
    Wt[idx] = f2b(v);
}

// ---------------- MFMA GEMM, LDS-staged B + register-ring A prefetch ----------------
template<int KDIM, int NTILES, bool A_BF16>
__global__ __launch_bounds__(256) void k_gemm_lds(const void* __restrict__ Ap,
                                                  const short* __restrict__ Wt,
                                                  short* __restrict__ C,
                                                  int M, int N)
{
    constexpr int NFULL = NTILES * 16;
    constexpr int KCH = 128;               // k-chunk
    constexpr int NK = KDIM / 32;          // total ksteps
    constexpr int NCH = KDIM / KCH;        // chunks
    constexpr int LROW = KCH + 8;          // shorts per LDS row
    __shared__ short Bs[NFULL * LROW];

    const int tid  = threadIdx.x;
    const int wave = tid >> 6;
    const int lane = tid & 63;
    const int quad = lane >> 4;
    const int col  = lane & 15;
    const int row  = blockIdx.x * 64 + wave * 16 + col;
    const int arow = row < M ? row : M - 1;

    f32x4 acc[NTILES];
    #pragma unroll
    for (int t = 0; t < NTILES; ++t) acc[t] = (f32x4){0.f, 0.f, 0.f, 0.f};

    bf16x8 arB[4];
    float4 arF[4][2];
    const short* Ab = (const short*)Ap;
    const float* Af = (const float*)Ap;
    auto pf = [&](int ks) {
        if (ks >= NK) return;
        if (A_BF16) {
            arB[ks & 3] = *(const bf16x8*)(Ab + (size_t)arow * KDIM + ks * 32 + quad * 8);
        } else {
            const float4* p = (const float4*)(Af + (size_t)arow * KDIM + ks * 32 + quad * 8);
            arF[ks & 3][0] = p[0];
            arF[ks & 3][1] = p[1];
        }
    };
    pf(0); pf(1); pf(2); pf(3);

    for (int c = 0; c < NCH; ++c) {
        const int k0 = c * KCH;
        constexpr int TOT8 = NFULL * (KCH / 8);
        #pragma unroll
        for (int i = tid; i < TOT8; i += 256) {
            int n  = i >> 4;
            int kk = i & 15;
            bf16x8 v = *(const bf16x8*)(Wt + (size_t)n * KDIM + k0 + kk * 8);
            *(bf16x8*)(Bs + n * LROW + kk * 8) = v;
        }
        __syncthreads();
        #pragma unroll
        for (int s = 0; s < KCH / 32; ++s) {
            const int ks = c * (KCH / 32) + s;
            bf16x8 afrag;
            if (A_BF16) {
                afrag = arB[ks & 3];
            } else {
                float4 v0 = arF[ks & 3][0], v1 = arF[ks & 3][1];
                afrag[0] = f2b(v0.x); afrag[1] = f2b(v0.y);
                afrag[2] = f2b(v0.z); afrag[3] = f2b(v0.w);
                afrag[4] = f2b(v1.x); afrag[5] = f2b(v1.y);
                afrag[6] = f2b(v1.z); afrag[7] = f2b(v1.w);
            }
            pf(ks + 4);
            #pragma unroll
            for (int t = 0; t < NTILES; ++t) {
                bf16x8 bfrag = *(const bf16x8*)(Bs + (t * 16 + col) * LROW + s * 32 + quad * 8);
                acc[t] = __builtin_amdgcn_mfma_f32_16x16x32_bf16(afrag, bfrag, acc[t], 0, 0, 0);
            }
        }
        if (c + 1 < NCH) __syncthreads();
    }

    const int mbase = blockIdx.x * 64 + wave * 16 + quad * 4;
    #pragma unroll
    for (int t = 0; t < NTILES; ++t) {
        int cc = t * 16 + col;
        if (cc < N) {
            #pragma unroll
            for (int r = 0; r < 4; ++r) {
                int m = mbase + r;
                if (m < M) C[(size_t)m * N + cc] = f2b(acc[t][r]);
            }
        }
    }
}

// ---------------- per-(node,head) attention logits from bf16 h ----------------
__global__ __launch_bounds__(256) void k_alpha(const unsigned short* __restrict__ h,
                                               const float* __restrict__ a_s,
                                               const float* __restrict__ a_d,
                                               float* __restrict__ as_o,
                                               float* __restrict__ ad_o)
{
    int idx = blockIdx.x * blockDim.x + threadIdx.x;   // n*NH + hh
    if (idx >= NN * NH) return;
    int hh = idx & (NH - 1);
    const uint4* hp = (const uint4*)(h + (size_t)idx * HIDC);
    uint4 q0 = hp[0], q1 = hp[1];
    unsigned int u[8] = {q0.x, q0.y, q0.z, q0.w, q1.x, q1.y, q1.z, q1.w};
    const float* ap = a_s + hh * HIDC;
    const float* dp = a_d + hh * HIDC;
    float ss = 0.f, dd = 0.f;
    #pragma unroll
    for (int i = 0; i < 8; ++i) {
        float f0 = blo(u[i]), f1 = bhi(u[i]);
        ss += f0 * ap[2 * i] + f1 * ap[2 * i + 1];
        dd += f0 * dp[2 * i] + f1 * dp[2 * i + 1];
    }
    as_o[idx] = ss;
    ad_o[idx] = dd;
}

__global__ __launch_bounds__(256) void k_alpha2(const unsigned short* __restrict__ h2,
                                                const float* __restrict__ a_s,
                                                const float* __restrict__ a_d,
                                                float* __restrict__ as_o,
                                                float* __restrict__ ad_o)
{
    int n = blockIdx.x * blockDim.x + threadIdx.x;
    if (n >= NN) return;
    const uint4* hp = (const uint4*)(h2 + (size_t)n * NLBL);
    float ss = 0.f, dd = 0.f;
    #pragma unroll
    for (int qi = 0; qi < 5; ++qi) {
        uint4 q = hp[qi];
        unsigned int u[4] = {q.x, q.y, q.z, q.w};
        #pragma unroll
        for (int j = 0; j < 4; ++j) {
            int c = qi * 8 + j * 2;
            float f0 = blo(u[j]), f1 = bhi(u[j]);
            ss += f0 * a_s[c] + f1 * a_s[c + 1];
            dd += f0 * a_d[c] + f1 * a_d[c + 1];
        }
    }
    as_o[n] = ss;
    ad_o[n] = dd;
}

// ---------------- CSR build ----------------
__global__ __launch_bounds__(256) void k_hist(const int* __restrict__ ei,
                                              int* __restrict__ deg)
{
    int e = blockIdx.x * blockDim.x + threadIdx.x;
    if (e >= ETOT) return;
    int dst = (e < EE) ? ei[EE + e] : (e - EE);
    atomicAdd(&deg[dst], 1);
}

__global__ __launch_bounds__(1024) void k_scan(const int* __restrict__ deg,
                                               int* __restrict__ row_ptr,
                                               int* __restrict__ cursor)
{
    __shared__ int sm[1024];
    __shared__ int carry;
    int tid = threadIdx.x;
    if (tid == 0) carry = 0;
    __syncthreads();
    for (int base = 0; base < NN; base += 8192) {
        int v[8];
        int s = 0;
        int i0 = base + tid * 8;
        #pragma unroll
        for (int j = 0; j < 8; ++j) {
            int i = i0 + j;
            v[j] = (i < NN) ? deg[i] : 0;
            s += v[j];
        }
        sm[tid] = s;
        __syncthreads();
        for (int ofs = 1; ofs < 1024; ofs <<= 1) {
            int t = (tid >= ofs) ? sm[tid - ofs] : 0;
            __syncthreads();
            sm[tid] += t;
            __syncthreads();
        }
        int excl = sm[tid] - s + carry;
        #pragma unroll
        for (int j = 0; j < 8; ++j) {
            int i = i0 + j;
            if (i < NN) { row_ptr[i] = excl; cursor[i] = excl; }
            excl += v[j];
        }
        int total = sm[1023];
        __syncthreads();
        if (tid == 0) carry += total;
        __syncthreads();
    }
    if (tid == 0) row_ptr[NN] = carry;   // == ETOT
}

__global__ __launch_bounds__(256) void k_scatter(const int* __restrict__ ei,
                                                 int* __restrict__ cursor,
                                                 int* __restrict__ csr_src)
{
    int e = blockIdx.x * blockDim.x + threadIdx.x;
    if (e >= ETOT) return;
    int src, dst;
    if (e < EE) { src = ei[e]; dst = ei[EE + e]; }
    else        { src = dst = e - EE; }
    int pos = atomicAdd(&cursor[dst], 1);
    csr_src[pos] = src;
}

// ---------------- pull aggregation: half-wave per edge stream, 4-deep unroll ----------------
// wave = 1 node; half-waves take alternating edges; 4 edges per half in flight (8/wave);
// __shfl_down(32) combine; fused softmax-norm + bias + BN + ELU -> packed bf16 store.
__global__ __launch_bounds__(256) void k_agg(const int* __restrict__ row_ptr,
                                             const int* __restrict__ csr_src,
                                             const unsigned short* __restrict__ h,
                                             const float* __restrict__ as,
                                             const float* __restrict__ ad,
                                             const float* __restrict__ b,
                                             const float* __restrict__ g,
                                             const float* __restrict__ be,
                                             const float* __restrict__ rm,
                                             const float* __restrict__ rv,
                                             short* __restrict__ out)
{
    int n = blockIdx.x * 4 + (threadIdx.x >> 6);
    if (n >= NN) return;
    int lane = threadIdx.x & 63;
    int half = lane >> 5;
    int c4 = lane & 31;                  // channel group: channels 4*c4 .. 4*c4+3
    int hh = c4 >> 2;                    // head
    float adv = ad[n * NH + hh];
    float a0 = 0.f, a1 = 0.f, a2 = 0.f, a3 = 0.f, sw = 0.f;
    int jb = row_ptr[n], je = row_ptr[n + 1];
    int j = jb + half;
    // 4-deep unroll per half-wave: edges j, j+2, j+4, j+6
    for (; j + 6 < je; j += 8) {
        int s0 = csr_src[j];
        int s1 = csr_src[j + 2];
        int s2 = csr_src[j + 4];
        int s3 = csr_src[j + 6];
        float l0 = as[s0 * NH + hh] + adv;
        float l1 = as[s1 * NH + hh] + adv;
        float l2 = as[s2 * NH + hh] + adv;
        float l3 = as[s3 * NH + hh] + adv;
        uint2 u0 = *(const uint2*)(h + (size_t)s0 * HCH + 4 * c4);
        uint2 u1 = *(const uint2*)(h + (size_t)s1 * HCH + 4 * c4);
        uint2 u2 = *(const uint2*)(h + (size_t)s2 * HCH + 4 * c4);
        uint2 u3 = *(const uint2*)(h + (size_t)s3 * HCH + 4 * c4);
        l0 = l0 > 0.f ? l0 : NEG_SLOPE * l0;
        l1 = l1 > 0.f ? l1 : NEG_SLOPE * l1;
        l2 = l2 > 0.f ? l2 : NEG_SLOPE * l2;
        l3 = l3 > 0.f ? l3 : NEG_SLOPE * l3;
        float w0 = __expf(l0), w1 = __expf(l1), w2 = __expf(l2), w3 = __expf(l3);
        sw += (w0 + w1) + (w2 + w3);
        a0 += w0 * blo(u0.x) + w1 * blo(u1.x) + w2 * blo(u2.x) + w3 * blo(u3.x);
        a1 += w0 * bhi(u0.x) + w1 * bhi(u1.x) + w2 * bhi(u2.x) + w3 * bhi(u3.x);
        a2 += w0 * blo(u0.y) + w1 * blo(u1.y) + w2 * blo(u2.y) + w3 * blo(u3.y);
        a3 += w0 * bhi(u0.y) + w1 * bhi(u1.y) + w2 * bhi(u2.y) + w3 * bhi(u3.y);
    }
    for (; j < je; j += 2) {
        int s0 = csr_src[j];
        float l0 = as[s0 * NH + hh] + adv;
        uint2 u0 = *(const uint2*)(h + (size_t)s0 * HCH + 4 * c4);
        l0 = l0 > 0.f ? l0 : NEG_SLOPE * l0;
        float w0 = __expf(l0);
        sw += w0;
        a0 += w0 * blo(u0.x);
        a1 += w0 * bhi(u0.x);
        a2 += w0 * blo(u0.y);
        a3 += w0 * bhi(u0.y);
    }
    // combine the two half-waves
    a0 += __shfl_down(a0, 32);
    a1 += __shfl_down(a1, 32);
    a2 += __shfl_down(a2, 32);
    a3 += __shfl_down(a3, 32);
    sw += __shfl_down(sw, 32);
    if (half == 0) {
        int c = 4 * c4;
        float inv = 1.f / (sw + 1e-16f);
        float4 bv  = *(const float4*)(b + c);
        float4 gv  = *(const float4*)(g + c);
        float4 bev = *(const float4*)(be + c);
        float4 rmv = *(const float4*)(rm + c);
        float4 rvv = *(const float4*)(rv + c);
        float r0 = a0 * inv + bv.x;
        float r1 = a1 * inv + bv.y;
        float r2 = a2 * inv + bv.z;
        float r3 = a3 * inv + bv.w;
        r0 = (r0 - rmv.x) * (gv.x * rsqrtf(rvv.x + BN_EPS)) + bev.x;
        r1 = (r1 - rmv.y) * (gv.y * rsqrtf(rvv.y + BN_EPS)) + bev.y;
        r2 = (r2 - rmv.z) * (gv.z * rsqrtf(rvv.z + BN_EPS)) + bev.z;
        r3 = (r3 - rmv.w) * (gv.w * rsqrtf(rvv.w + BN_EPS)) + bev.w;
        r0 = r0 > 0.f ? r0 : ELU_A * expm1f(r0);
        r1 = r1 > 0.f ? r1 : ELU_A * expm1f(r1);
        r2 = r2 > 0.f ? r2 : ELU_A * expm1f(r2);
        r3 = r3 > 0.f ? r3 : ELU_A * expm1f(r3);
        unsigned int lo = (unsigned int)(unsigned short)f2b(r0) |
                          ((unsigned int)(unsigned short)f2b(r1) << 16);
        unsigned int hi = (unsigned int)(unsigned short)f2b(r2) |
                          ((unsigned int)(unsigned short)f2b(r3) << 16);
        *(uint2*)(out + (size_t)n * HCH + c) = make_uint2(lo, hi);
    }
}

// layer-2: 1 head, 40 ch bf16 gather, half-wave per edge stream, 4-deep unroll, fp32 out
__global__ __launch_bounds__(256) void k_agg2(const int* __restrict__ row_ptr,
                                              const int* __restrict__ csr_src,
                                              const unsigned short* __restrict__ h2,
                                              const float* __restrict__ as,
                                              const float* __restrict__ ad,
                                              const float* __restrict__ b,
                                              float* __restrict__ out)
{
    int n = blockIdx.x * 4 + (threadIdx.x >> 6);
    if (n >= NN) return;
    int lane = threadIdx.x & 63;
    int half = lane >> 5;                // which edge stream
    int c2 = lane & 31;                  // channel-pair index; active if c2 < 20
    bool act = c2 < 20;
    int coff = act ? 2 * c2 : 0;
    float adv = ad[n];
    float acc0 = 0.f, acc1 = 0.f, sw = 0.f;
    int jb = row_ptr[n], je = row_ptr[n + 1];
    int j = jb + half;
    for (; j + 6 < je; j += 8) {
        int s0 = csr_src[j];
        int s1 = csr_src[j + 2];
        int s2 = csr_src[j + 4];
        int s3 = csr_src[j + 6];
        float l0 = as[s0] + adv;
        float l1 = as[s1] + adv;
        float l2 = as[s2] + adv;
        float l3 = as[s3] + adv;
        unsigned int u0 = *(const unsigned int*)(h2 + (size_t)s0 * NLBL + coff);
        unsigned int u1 = *(const unsigned int*)(h2 + (size_t)s1 * NLBL + coff);
        unsigned int u2 = *(const unsigned int*)(h2 + (size_t)s2 * NLBL + coff);
        unsigned int u3 = *(const unsigned int*)(h2 + (size_t)s3 * NLBL + coff);
        l0 = l0 > 0.f ? l0 : NEG_SLOPE * l0;
        l1 = l1 > 0.f ? l1 : NEG_SLOPE * l1;
        l2 = l2 > 0.f ? l2 : NEG_SLOPE * l2;
        l3 = l3 > 0.f ? l3 : NEG_SLOPE * l3;
        float w0 = __expf(l0), w1 = __expf(l1), w2 = __expf(l2), w3 = __expf(l3);
        sw += (w0 + w1) + (w2 + w3);
        if (act) {
            acc0 += w0 * blo(u0) + w1 * blo(u1) + w2 * blo(u2) + w3 * blo(u3);
            acc1 += w0 * bhi(u0) + w1 * bhi(u1) + w2 * bhi(u2) + w3 * bhi(u3);
        }
    }
    for (; j < je; j += 2) {
        int s = csr_src[j];
        float l = as[s] + adv;
        unsigned int u = *(const unsigned int*)(h2 + (size_t)s * NLBL + coff);
        l = l > 0.f ? l : NEG_SLOPE * l;
        float w = __expf(l);
        sw += w;
        if (act) {
            acc0 += w * blo(u);
            acc1 += w * bhi(u);
        }
    }
    float acc0b = __shfl_down(acc0, 32);
    float acc1b = __shfl_down(acc1, 32);
    float swb   = __shfl_down(sw, 32);
    if (half == 0 && act) {
        acc0 += acc0b; acc1 += acc1b; sw += swb;
        float inv = 1.f / (sw + 1e-16f);
        out[(size_t)n * NLBL + 2 * c2]     = acc0 * inv + b[2 * c2];
        out[(size_t)n * NLBL + 2 * c2 + 1] = acc1 * inv + b[2 * c2 + 1];
    }
}

extern "C" void kernel_launch(void* const* d_in, const int* in_sizes, int n_in,
                              void* d_out, int out_size, void* d_ws, size_t ws_size,
                              hipStream_t stream)
{
    const float* x   = (const float*)d_in[0];
    const int*   ei  = (const int*)d_in[1];
    const float* W0  = (const float*)d_in[2];
    const float* as0 = (const float*)d_in[3];
    const float* ad0 = (const float*)d_in[4];
    const float* b0  = (const float*)d_in[5];
    const float* g0  = (const float*)d_in[6];
    const float* be0 = (const float*)d_in[7];
    const float* rm0 = (const float*)d_in[8];
    const float* rv0 = (const float*)d_in[9];
    const float* W1  = (const float*)d_in[10];
    const float* as1 = (const float*)d_in[11];
    const float* ad1 = (const float*)d_in[12];
    const float* b1  = (const float*)d_in[13];
    const float* g1  = (const float*)d_in[14];
    const float* be1 = (const float*)d_in[15];
    const float* rm1 = (const float*)d_in[16];
    const float* rv1 = (const float*)d_in[17];
    const float* W2  = (const float*)d_in[18];
    const float* a_s2 = (const float*)d_in[19];
    const float* a_d2 = (const float*)d_in[20];
    const float* b2  = (const float*)d_in[21];
    float* out = (float*)d_out;

    char* ws = (char*)d_ws;
    size_t off = 0;
    auto alloc = [&](size_t bytes) {
        void* p = (void*)(ws + off);
        off += (bytes + 255) & ~(size_t)255;
        return p;
    };
    short* hbuf   = (short*)alloc((size_t)NN * HCH * 2);   // bf16 GEMM out / gather source
    short* fbuf   = (short*)alloc((size_t)NN * HCH * 2);   // bf16 aggregated features (GEMM A input)
    float* asb    = (float*)alloc((size_t)NN * NH * 4);
    float* adb    = (float*)alloc((size_t)NN * NH * 4);
    int*   deg    = (int*)alloc((size_t)NN * 4);
    int*   rowp   = (int*)alloc((size_t)(NN + 1) * 4);
    int*   cursor = (int*)alloc((size_t)NN * 4);
    int*   csrs   = (int*)alloc((size_t)ETOT * 4);
    short* Wt0    = (short*)alloc((size_t)HCH * FIN * 2);
    short* Wt1    = (short*)alloc((size_t)HCH * HCH * 2);
    short* Wt2    = (short*)alloc((size_t)NLBLP * HCH * 2);
    short* h2     = hbuf;   // reuse: hbuf dead by layer 2

    const int T = 256;
    const int gE  = (ETOT + T - 1) / T;
    const int gNH = (NN * NH + T - 1) / T;
    const int gN4 = (NN + 3) / 4;
    const int gM  = (NN + 63) / 64;

    // ---------- weight prep ----------
    k_convW<<<(HCH * FIN + T - 1) / T, T, 0, stream>>>(W0, Wt0, FIN, HCH, HCH);
    k_convW<<<(HCH * HCH + T - 1) / T, T, 0, stream>>>(W1, Wt1, HCH, HCH, HCH);
    k_convW<<<(NLBLP * HCH + T - 1) / T, T, 0, stream>>>(W2, Wt2, HCH, NLBL, NLBLP);

    // ---------- CSR build (reused by all 3 layers) ----------
    hipMemsetAsync(deg, 0, (size_t)NN * 4, stream);
    k_hist<<<gE, T, 0, stream>>>(ei, deg);
    k_scan<<<1, 1024, 0, stream>>>(deg, rowp, cursor);
    k_scatter<<<gE, T, 0, stream>>>(ei, cursor, csrs);

    // ---------- layer 0 ----------
    k_gemm_lds<FIN, 8, false><<<gM, T, 0, stream>>>(x, Wt0, hbuf, NN, HCH);
    k_alpha<<<gNH, T, 0, stream>>>((const unsigned short*)hbuf, as0, ad0, asb, adb);
    k_agg<<<gN4, T, 0, stream>>>(rowp, csrs, (const unsigned short*)hbuf, asb, adb,
                                 b0, g0, be0, rm0, rv0, fbuf);

    // ---------- layer 1 ----------
    k_gemm_lds<HCH, 8, true><<<gM, T, 0, stream>>>(fbuf, Wt1, hbuf, NN, HCH);
    k_alpha<<<gNH, T, 0, stream>>>((const unsigned short*)hbuf, as1, ad1, asb, adb);
    k_agg<<<gN4, T, 0, stream>>>(rowp, csrs, (const unsigned short*)hbuf, asb, adb,
                                 b1, g1, be1, rm1, rv1, fbuf);

    // ---------- layer 2 ----------
    k_gemm_lds<HCH, 3, true><<<gM, T, 0, stream>>>(fbuf, Wt2, h2, NN, NLBL);
    k_alpha2<<<(NN + T - 1) / T, T, 0, stream>>>((const unsigned short*)h2, a_s2, a_d2, asb, adb);
    k_agg2<<<gN4, T, 0, stream>>>(rowp, csrs, (const unsigned short*)h2, asb, adb, b2, out);
}

// Round 8
// 475.158 us; speedup vs baseline: 27.7426x; 1.0069x over previous
//
#include <hip/hip_runtime.h>
#include <hip/hip_bf16.h>
#include <cstdint>
#include <cstddef>

#define NN 50000
#define EE 800000
#define FIN 512
#define HIDC 16
#define NH 8
#define HCH 128
#define NLBL 40
#define NLBLP 48
#define ETOT (EE + NN)
#define NEG_SLOPE 0.2f
#define ELU_A 0.2f
#define BN_EPS 1e-5f

typedef __attribute__((ext_vector_type(8))) short bf16x8;
typedef __attribute__((ext_vector_type(4))) float f32x4;

__device__ inline short f2b(float f) {
    __hip_bfloat16 h = __float2bfloat16(f);   // RNE
    return *reinterpret_cast<short*>(&h);
}
__device__ inline float blo(unsigned int u) {
    union { unsigned int u; float f; } v; v.u = u << 16; return v.f;
}
__device__ inline float bhi(unsigned int u) {
    union { unsigned int u; float f; } v; v.u = u & 0xffff0000u; return v.f;
}

// ---------------- weight transpose + bf16 convert: Wt[n][k] = bf16(W[k][n]) ----------------
__global__ __launch_bounds__(256) void k_convW(const float* __restrict__ W,
                                               short* __restrict__ Wt,
                                               int K, int N, int Np)
{
    int idx = blockIdx.x * blockDim.x + threadIdx.x;
    if (idx >= Np * K) return;
    int n = idx / K, k = idx - n * K;
    float v = (n < N) ? W[(size_t)k * N + n] : 0.f;
    Wt[idx] = f2b(v);
}

// ---------------- MFMA GEMM, LDS-staged B + register-ring A prefetch ----------------
// grid.y = column block (NTILES*16 cols each); smaller LDS -> higher occupancy.
template<int KDIM, int NTILES, bool A_BF16>
__global__ __launch_bounds__(256) void k_gemm_lds(const void* __restrict__ Ap,
                                                  const short* __restrict__ Wt,
                                                  short* __restrict__ C,
                                                  int M, int N)
{
    constexpr int NFULL = NTILES * 16;
    constexpr int KCH = 128;               // k-chunk
    constexpr int NK = KDIM / 32;          // total ksteps
    constexpr int NCH = KDIM / KCH;        // chunks
    constexpr int LROW = KCH + 8;          // shorts per LDS row
    __shared__ short Bs[NFULL * LROW];

    const int tid  = threadIdx.x;
    const int wave = tid >> 6;
    const int lane = tid & 63;
    const int quad = lane >> 4;
    const int col  = lane & 15;
    const int cb   = blockIdx.y * NFULL;   // column base
    const int row  = blockIdx.x * 64 + wave * 16 + col;
    const int arow = row < M ? row : M - 1;

    f32x4 acc[NTILES];
    #pragma unroll
    for (int t = 0; t < NTILES; ++t) acc[t] = (f32x4){0.f, 0.f, 0.f, 0.f};

    bf16x8 arB[4];
    float4 arF[4][2];
    const short* Ab = (const short*)Ap;
    const float* Af = (const float*)Ap;
    auto pf = [&](int ks) {
        if (ks >= NK) return;
        if (A_BF16) {
            arB[ks & 3] = *(const bf16x8*)(Ab + (size_t)arow * KDIM + ks * 32 + quad * 8);
        } else {
            const float4* p = (const float4*)(Af + (size_t)arow * KDIM + ks * 32 + quad * 8);
            arF[ks & 3][0] = p[0];
            arF[ks & 3][1] = p[1];
        }
    };
    pf(0); pf(1); pf(2); pf(3);

    for (int c = 0; c < NCH; ++c) {
        const int k0 = c * KCH;
        constexpr int TOT8 = NFULL * (KCH / 8);
        #pragma unroll
        for (int i = tid; i < TOT8; i += 256) {
            int n  = i >> 4;
            int kk = i & 15;
            bf16x8 v = *(const bf16x8*)(Wt + (size_t)(cb + n) * KDIM + k0 + kk * 8);
            *(bf16x8*)(Bs + n * LROW + kk * 8) = v;
        }
        __syncthreads();
        #pragma unroll
        for (int s = 0; s < KCH / 32; ++s) {
            const int ks = c * (KCH / 32) + s;
            bf16x8 afrag;
            if (A_BF16) {
                afrag = arB[ks & 3];
            } else {
                float4 v0 = arF[ks & 3][0], v1 = arF[ks & 3][1];
                afrag[0] = f2b(v0.x); afrag[1] = f2b(v0.y);
                afrag[2] = f2b(v0.z); afrag[3] = f2b(v0.w);
                afrag[4] = f2b(v1.x); afrag[5] = f2b(v1.y);
                afrag[6] = f2b(v1.z); afrag[7] = f2b(v1.w);
            }
            pf(ks + 4);
            #pragma unroll
            for (int t = 0; t < NTILES; ++t) {
                bf16x8 bfrag = *(const bf16x8*)(Bs + (t * 16 + col) * LROW + s * 32 + quad * 8);
                acc[t] = __builtin_amdgcn_mfma_f32_16x16x32_bf16(afrag, bfrag, acc[t], 0, 0, 0);
            }
        }
        if (c + 1 < NCH) __syncthreads();
    }

    const int mbase = blockIdx.x * 64 + wave * 16 + quad * 4;
    #pragma unroll
    for (int t = 0; t < NTILES; ++t) {
        int cc = cb + t * 16 + col;
        if (cc < N) {
            #pragma unroll
            for (int r = 0; r < 4; ++r) {
                int m = mbase + r;
                if (m < M) C[(size_t)m * N + cc] = f2b(acc[t][r]);
            }
        }
    }
}

// ---------------- per-(node,head) attention logits from bf16 h ----------------
__global__ __launch_bounds__(256) void k_alpha(const unsigned short* __restrict__ h,
                                               const float* __restrict__ a_s,
                                               const float* __restrict__ a_d,
                                               float* __restrict__ as_o,
                                               float* __restrict__ ad_o)
{
    int idx = blockIdx.x * blockDim.x + threadIdx.x;   // n*NH + hh
    if (idx >= NN * NH) return;
    int hh = idx & (NH - 1);
    const uint4* hp = (const uint4*)(h + (size_t)idx * HIDC);
    uint4 q0 = hp[0], q1 = hp[1];
    unsigned int u[8] = {q0.x, q0.y, q0.z, q0.w, q1.x, q1.y, q1.z, q1.w};
    const float* ap = a_s + hh * HIDC;
    const float* dp = a_d + hh * HIDC;
    float ss = 0.f, dd = 0.f;
    #pragma unroll
    for (int i = 0; i < 8; ++i) {
        float f0 = blo(u[i]), f1 = bhi(u[i]);
        ss += f0 * ap[2 * i] + f1 * ap[2 * i + 1];
        dd += f0 * dp[2 * i] + f1 * dp[2 * i + 1];
    }
    as_o[idx] = ss;
    ad_o[idx] = dd;
}

__global__ __launch_bounds__(256) void k_alpha2(const unsigned short* __restrict__ h2,
                                                const float* __restrict__ a_s,
                                                const float* __restrict__ a_d,
                                                float* __restrict__ as_o,
                                                float* __restrict__ ad_o)
{
    int n = blockIdx.x * blockDim.x + threadIdx.x;
    if (n >= NN) return;
    const uint4* hp = (const uint4*)(h2 + (size_t)n * NLBL);
    float ss = 0.f, dd = 0.f;
    #pragma unroll
    for (int qi = 0; qi < 5; ++qi) {
        uint4 q = hp[qi];
        unsigned int u[4] = {q.x, q.y, q.z, q.w};
        #pragma unroll
        for (int j = 0; j < 4; ++j) {
            int c = qi * 8 + j * 2;
            float f0 = blo(u[j]), f1 = bhi(u[j]);
            ss += f0 * a_s[c] + f1 * a_s[c + 1];
            dd += f0 * a_d[c] + f1 * a_d[c + 1];
        }
    }
    as_o[n] = ss;
    ad_o[n] = dd;
}

// ---------------- CSR build ----------------
__global__ __launch_bounds__(256) void k_hist(const int* __restrict__ ei,
                                              int* __restrict__ deg)
{
    int e = blockIdx.x * blockDim.x + threadIdx.x;
    if (e >= ETOT) return;
    int dst = (e < EE) ? ei[EE + e] : (e - EE);
    atomicAdd(&deg[dst], 1);
}

__global__ __launch_bounds__(1024) void k_scan(const int* __restrict__ deg,
                                               int* __restrict__ row_ptr,
                                               int* __restrict__ cursor)
{
    __shared__ int sm[1024];
    __shared__ int carry;
    int tid = threadIdx.x;
    if (tid == 0) carry = 0;
    __syncthreads();
    for (int base = 0; base < NN; base += 8192) {
        int v[8];
        int s = 0;
        int i0 = base + tid * 8;
        #pragma unroll
        for (int j = 0; j < 8; ++j) {
            int i = i0 + j;
            v[j] = (i < NN) ? deg[i] : 0;
            s += v[j];
        }
        sm[tid] = s;
        __syncthreads();
        for (int ofs = 1; ofs < 1024; ofs <<= 1) {
            int t = (tid >= ofs) ? sm[tid - ofs] : 0;
            __syncthreads();
            sm[tid] += t;
            __syncthreads();
        }
        int excl = sm[tid] - s + carry;
        #pragma unroll
        for (int j = 0; j < 8; ++j) {
            int i = i0 + j;
            if (i < NN) { row_ptr[i] = excl; cursor[i] = excl; }
            excl += v[j];
        }
        int total = sm[1023];
        __syncthreads();
        if (tid == 0) carry += total;
        __syncthreads();
    }
    if (tid == 0) row_ptr[NN] = carry;   // == ETOT
}

__global__ __launch_bounds__(256) void k_scatter(const int* __restrict__ ei,
                                                 int* __restrict__ cursor,
                                                 int* __restrict__ csr_src)
{
    int e = blockIdx.x * blockDim.x + threadIdx.x;
    if (e >= ETOT) return;
    int src, dst;
    if (e < EE) { src = ei[e]; dst = ei[EE + e]; }
    else        { src = dst = e - EE; }
    int pos = atomicAdd(&cursor[dst], 1);
    csr_src[pos] = src;
}

// ---------------- pull aggregation: half-wave per edge stream, 4-deep unroll ----------------
__global__ __launch_bounds__(256) void k_agg(const int* __restrict__ row_ptr,
                                             const int* __restrict__ csr_src,
                                             const unsigned short* __restrict__ h,
                                             const float* __restrict__ as,
                                             const float* __restrict__ ad,
                                             const float* __restrict__ b,
                                             const float* __restrict__ g,
                                             const float* __restrict__ be,
                                             const float* __restrict__ rm,
                                             const float* __restrict__ rv,
                                             short* __restrict__ out)
{
    int n = blockIdx.x * 4 + (threadIdx.x >> 6);
    if (n >= NN) return;
    int lane = threadIdx.x & 63;
    int half = lane >> 5;
    int c4 = lane & 31;                  // channel group: channels 4*c4 .. 4*c4+3
    int hh = c4 >> 2;                    // head
    float adv = ad[n * NH + hh];
    float a0 = 0.f, a1 = 0.f, a2 = 0.f, a3 = 0.f, sw = 0.f;
    int jb = row_ptr[n], je = row_ptr[n + 1];
    int j = jb + half;
    for (; j + 6 < je; j += 8) {
        int s0 = csr_src[j];
        int s1 = csr_src[j + 2];
        int s2 = csr_src[j + 4];
        int s3 = csr_src[j + 6];
        float l0 = as[s0 * NH + hh] + adv;
        float l1 = as[s1 * NH + hh] + adv;
        float l2 = as[s2 * NH + hh] + adv;
        float l3 = as[s3 * NH + hh] + adv;
        uint2 u0 = *(const uint2*)(h + (size_t)s0 * HCH + 4 * c4);
        uint2 u1 = *(const uint2*)(h + (size_t)s1 * HCH + 4 * c4);
        uint2 u2 = *(const uint2*)(h + (size_t)s2 * HCH + 4 * c4);
        uint2 u3 = *(const uint2*)(h + (size_t)s3 * HCH + 4 * c4);
        l0 = l0 > 0.f ? l0 : NEG_SLOPE * l0;
        l1 = l1 > 0.f ? l1 : NEG_SLOPE * l1;
        l2 = l2 > 0.f ? l2 : NEG_SLOPE * l2;
        l3 = l3 > 0.f ? l3 : NEG_SLOPE * l3;
        float w0 = __expf(l0), w1 = __expf(l1), w2 = __expf(l2), w3 = __expf(l3);
        sw += (w0 + w1) + (w2 + w3);
        a0 += w0 * blo(u0.x) + w1 * blo(u1.x) + w2 * blo(u2.x) + w3 * blo(u3.x);
        a1 += w0 * bhi(u0.x) + w1 * bhi(u1.x) + w2 * bhi(u2.x) + w3 * bhi(u3.x);
        a2 += w0 * blo(u0.y) + w1 * blo(u1.y) + w2 * blo(u2.y) + w3 * blo(u3.y);
        a3 += w0 * bhi(u0.y) + w1 * bhi(u1.y) + w2 * bhi(u2.y) + w3 * bhi(u3.y);
    }
    for (; j < je; j += 2) {
        int s0 = csr_src[j];
        float l0 = as[s0 * NH + hh] + adv;
        uint2 u0 = *(const uint2*)(h + (size_t)s0 * HCH + 4 * c4);
        l0 = l0 > 0.f ? l0 : NEG_SLOPE * l0;
        float w0 = __expf(l0);
        sw += w0;
        a0 += w0 * blo(u0.x);
        a1 += w0 * bhi(u0.x);
        a2 += w0 * blo(u0.y);
        a3 += w0 * bhi(u0.y);
    }
    // combine the two half-waves
    a0 += __shfl_down(a0, 32);
    a1 += __shfl_down(a1, 32);
    a2 += __shfl_down(a2, 32);
    a3 += __shfl_down(a3, 32);
    sw += __shfl_down(sw, 32);
    if (half == 0) {
        int c = 4 * c4;
        float inv = 1.f / (sw + 1e-16f);
        float4 bv  = *(const float4*)(b + c);
        float4 gv  = *(const float4*)(g + c);
        float4 bev = *(const float4*)(be + c);
        float4 rmv = *(const float4*)(rm + c);
        float4 rvv = *(const float4*)(rv + c);
        float r0 = a0 * inv + bv.x;
        float r1 = a1 * inv + bv.y;
        float r2 = a2 * inv + bv.z;
        float r3 = a3 * inv + bv.w;
        r0 = (r0 - rmv.x) * (gv.x * rsqrtf(rvv.x + BN_EPS)) + bev.x;
        r1 = (r1 - rmv.y) * (gv.y * rsqrtf(rvv.y + BN_EPS)) + bev.y;
        r2 = (r2 - rmv.z) * (gv.z * rsqrtf(rvv.z + BN_EPS)) + bev.z;
        r3 = (r3 - rmv.w) * (gv.w * rsqrtf(rvv.w + BN_EPS)) + bev.w;
        r0 = r0 > 0.f ? r0 : ELU_A * expm1f(r0);
        r1 = r1 > 0.f ? r1 : ELU_A * expm1f(r1);
        r2 = r2 > 0.f ? r2 : ELU_A * expm1f(r2);
        r3 = r3 > 0.f ? r3 : ELU_A * expm1f(r3);
        unsigned int lo = (unsigned int)(unsigned short)f2b(r0) |
                          ((unsigned int)(unsigned short)f2b(r1) << 16);
        unsigned int hi = (unsigned int)(unsigned short)f2b(r2) |
                          ((unsigned int)(unsigned short)f2b(r3) << 16);
        *(uint2*)(out + (size_t)n * HCH + c) = make_uint2(lo, hi);
    }
}

// layer-2: 1 head, 40 ch bf16 gather, half-wave per edge stream, 4-deep unroll, fp32 out
__global__ __launch_bounds__(256) void k_agg2(const int* __restrict__ row_ptr,
                                              const int* __restrict__ csr_src,
                                              const unsigned short* __restrict__ h2,
                                              const float* __restrict__ as,
                                              const float* __restrict__ ad,
                                              const float* __restrict__ b,
                                              float* __restrict__ out)
{
    int n = blockIdx.x * 4 + (threadIdx.x >> 6);
    if (n >= NN) return;
    int lane = threadIdx.x & 63;
    int half = lane >> 5;                // which edge stream
    int c2 = lane & 31;                  // channel-pair index; active if c2 < 20
    bool act = c2 < 20;
    int coff = act ? 2 * c2 : 0;
    float adv = ad[n];
    float acc0 = 0.f, acc1 = 0.f, sw = 0.f;
    int jb = row_ptr[n], je = row_ptr[n + 1];
    int j = jb + half;
    for (; j + 6 < je; j += 8) {
        int s0 = csr_src[j];
        int s1 = csr_src[j + 2];
        int s2 = csr_src[j + 4];
        int s3 = csr_src[j + 6];
        float l0 = as[s0] + adv;
        float l1 = as[s1] + adv;
        float l2 = as[s2] + adv;
        float l3 = as[s3] + adv;
        unsigned int u0 = *(const unsigned int*)(h2 + (size_t)s0 * NLBL + coff);
        unsigned int u1 = *(const unsigned int*)(h2 + (size_t)s1 * NLBL + coff);
        unsigned int u2 = *(const unsigned int*)(h2 + (size_t)s2 * NLBL + coff);
        unsigned int u3 = *(const unsigned int*)(h2 + (size_t)s3 * NLBL + coff);
        l0 = l0 > 0.f ? l0 : NEG_SLOPE * l0;
        l1 = l1 > 0.f ? l1 : NEG_SLOPE * l1;
        l2 = l2 > 0.f ? l2 : NEG_SLOPE * l2;
        l3 = l3 > 0.f ? l3 : NEG_SLOPE * l3;
        float w0 = __expf(l0), w1 = __expf(l1), w2 = __expf(l2), w3 = __expf(l3);
        sw += (w0 + w1) + (w2 + w3);
        if (act) {
            acc0 += w0 * blo(u0) + w1 * blo(u1) + w2 * blo(u2) + w3 * blo(u3);
            acc1 += w0 * bhi(u0) + w1 * bhi(u1) + w2 * bhi(u2) + w3 * bhi(u3);
        }
    }
    for (; j < je; j += 2) {
        int s = csr_src[j];
        float l = as[s] + adv;
        unsigned int u = *(const unsigned int*)(h2 + (size_t)s * NLBL + coff);
        l = l > 0.f ? l : NEG_SLOPE * l;
        float w = __expf(l);
        sw += w;
        if (act) {
            acc0 += w * blo(u);
            acc1 += w * bhi(u);
        }
    }
    float acc0b = __shfl_down(acc0, 32);
    float acc1b = __shfl_down(acc1, 32);
    float swb   = __shfl_down(sw, 32);
    if (half == 0 && act) {
        acc0 += acc0b; acc1 += acc1b; sw += swb;
        float inv = 1.f / (sw + 1e-16f);
        out[(size_t)n * NLBL + 2 * c2]     = acc0 * inv + b[2 * c2];
        out[(size_t)n * NLBL + 2 * c2 + 1] = acc1 * inv + b[2 * c2 + 1];
    }
}

extern "C" void kernel_launch(void* const* d_in, const int* in_sizes, int n_in,
                              void* d_out, int out_size, void* d_ws, size_t ws_size,
                              hipStream_t stream)
{
    const float* x   = (const float*)d_in[0];
    const int*   ei  = (const int*)d_in[1];
    const float* W0  = (const float*)d_in[2];
    const float* as0 = (const float*)d_in[3];
    const float* ad0 = (const float*)d_in[4];
    const float* b0  = (const float*)d_in[5];
    const float* g0  = (const float*)d_in[6];
    const float* be0 = (const float*)d_in[7];
    const float* rm0 = (const float*)d_in[8];
    const float* rv0 = (const float*)d_in[9];
    const float* W1  = (const float*)d_in[10];
    const float* as1 = (const float*)d_in[11];
    const float* ad1 = (const float*)d_in[12];
    const float* b1  = (const float*)d_in[13];
    const float* g1  = (const float*)d_in[14];
    const float* be1 = (const float*)d_in[15];
    const float* rm1 = (const float*)d_in[16];
    const float* rv1 = (const float*)d_in[17];
    const float* W2  = (const float*)d_in[18];
    const float* a_s2 = (const float*)d_in[19];
    const float* a_d2 = (const float*)d_in[20];
    const float* b2  = (const float*)d_in[21];
    float* out = (float*)d_out;

    char* ws = (char*)d_ws;
    size_t off = 0;
    auto alloc = [&](size_t bytes) {
        void* p = (void*)(ws + off);
        off += (bytes + 255) & ~(size_t)255;
        return p;
    };
    short* hbuf   = (short*)alloc((size_t)NN * HCH * 2);   // bf16 GEMM out / gather source
    short* fbuf   = (short*)alloc((size_t)NN * HCH * 2);   // bf16 aggregated features (GEMM A input)
    float* asb    = (float*)alloc((size_t)NN * NH * 4);
    float* adb    = (float*)alloc((size_t)NN * NH * 4);
    int*   deg    = (int*)alloc((size_t)NN * 4);
    int*   rowp   = (int*)alloc((size_t)(NN + 1) * 4);
    int*   cursor = (int*)alloc((size_t)NN * 4);
    int*   csrs   = (int*)alloc((size_t)ETOT * 4);
    short* Wt0    = (short*)alloc((size_t)HCH * FIN * 2);
    short* Wt1    = (short*)alloc((size_t)HCH * HCH * 2);
    short* Wt2    = (short*)alloc((size_t)NLBLP * HCH * 2);
    short* h2     = hbuf;   // reuse: hbuf dead by layer 2

    const int T = 256;
    const int gE  = (ETOT + T - 1) / T;
    const int gNH = (NN * NH + T - 1) / T;
    const int gN4 = (NN + 3) / 4;
    const int gM  = (NN + 63) / 64;

    // ---------- weight prep ----------
    k_convW<<<(HCH * FIN + T - 1) / T, T, 0, stream>>>(W0, Wt0, FIN, HCH, HCH);
    k_convW<<<(HCH * HCH + T - 1) / T, T, 0, stream>>>(W1, Wt1, HCH, HCH, HCH);
    k_convW<<<(NLBLP * HCH + T - 1) / T, T, 0, stream>>>(W2, Wt2, HCH, NLBL, NLBLP);

    // ---------- CSR build (reused by all 3 layers) ----------
    hipMemsetAsync(deg, 0, (size_t)NN * 4, stream);
    k_hist<<<gE, T, 0, stream>>>(ei, deg);
    k_scan<<<1, 1024, 0, stream>>>(deg, rowp, cursor);
    k_scatter<<<gE, T, 0, stream>>>(ei, cursor, csrs);

    // ---------- layer 0 ----------
    k_gemm_lds<FIN, 4, false><<<dim3(gM, 2), T, 0, stream>>>(x, Wt0, hbuf, NN, HCH);
    k_alpha<<<gNH, T, 0, stream>>>((const unsigned short*)hbuf, as0, ad0, asb, adb);
    k_agg<<<gN4, T, 0, stream>>>(rowp, csrs, (const unsigned short*)hbuf, asb, adb,
                                 b0, g0, be0, rm0, rv0, fbuf);

    // ---------- layer 1 ----------
    k_gemm_lds<HCH, 4, true><<<dim3(gM, 2), T, 0, stream>>>(fbuf, Wt1, hbuf, NN, HCH);
    k_alpha<<<gNH, T, 0, stream>>>((const unsigned short*)hbuf, as1, ad1, asb, adb);
    k_agg<<<gN4, T, 0, stream>>>(rowp, csrs, (const unsigned short*)hbuf, asb, adb,
                                 b1, g1, be1, rm1, rv1, fbuf);

    // ---------- layer 2 ----------
    k_gemm_lds<HCH, 3, true><<<dim3(gM, 1), T, 0, stream>>>(fbuf, Wt2, h2, NN, NLBL);
    k_alpha2<<<(NN + T - 1) / T, T, 0, stream>>>((const unsigned short*)h2, a_s2, a_d2, asb, adb);
    k_agg2<<<gN4, T, 0, stream>>>(rowp, csrs, (const unsigned short*)h2, asb, adb, b2, out);
}